// Round 13
// baseline (693.793 us; speedup 1.0000x reference)
//
#include <hip/hip_runtime.h>
#include <hip/hip_bf16.h>

#define NN 8192
#define HH 4096
#define GG 8
#define STR 128            // fixed stride for per-node edge lists (max deg ~57)
#define NCH 32             // H chunks (128 cols = 2 MB/chunk in bf16)
#define PRG 64             // pool row-groups (partial-reduction factor)
#define FJG 32             // final j-groups

typedef unsigned uint4n __attribute__((ext_vector_type(4)));  // native vec for NT stores

// ---------------------------------------------------------------------------
// bf16 helpers (packed 2x bf16 per u32; element 2q in low 16 bits)
// ---------------------------------------------------------------------------
__device__ inline unsigned bf16rne(float f) {
    unsigned u = __float_as_uint(f);
    unsigned r = 0x7fffu + ((u >> 16) & 1u);
    return (u + r) >> 16;
}
__device__ inline unsigned pack2(float lo, float hi) {
    return bf16rne(lo) | (bf16rne(hi) << 16);
}
__device__ inline void nt_store16(void* p, unsigned a, unsigned b, unsigned c, unsigned d) {
    uint4n v; v.x = a; v.y = b; v.z = c; v.w = d;
    __builtin_nontemporal_store(v, reinterpret_cast<uint4n*>(p));
}
// acc (2 elems) += unpacked u32 via packed add
__device__ inline void acc2p(float2& acc, unsigned u) {
    float2 t;
    t.x = __uint_as_float(u << 16);
    t.y = __uint_as_float(u & 0xffff0000u);
    asm("v_pk_add_f32 %0, %1, %0" : "+v"(acc) : "v"(t));
}
__device__ inline void unpack8(uint4 v, float* __restrict__ h) {
    const unsigned* pu = reinterpret_cast<const unsigned*>(&v);
    #pragma unroll
    for (int q = 0; q < 4; ++q) {
        const unsigned u = pu[q];
        h[2 * q]     = __uint_as_float(u << 16);
        h[2 * q + 1] = __uint_as_float(u & 0xffff0000u);
    }
}

// fp32 -> packed bf16; 8 elems per thread (streaming store: no L2 allocate)
__global__ __launch_bounds__(256) void k_cvt(const float* __restrict__ src,
                                             uint4* __restrict__ dst) {
    const size_t i = (size_t)blockIdx.x * 256 + threadIdx.x;
    const float4 a = reinterpret_cast<const float4*>(src)[2 * i];
    const float4 b = reinterpret_cast<const float4*>(src)[2 * i + 1];
    nt_store16(&dst[i], pack2(a.x, a.y), pack2(a.z, a.w),
                        pack2(b.x, b.y), pack2(b.z, b.w));
}

// ---------------------------------------------------------------------------
// Single-pass graph build (reads x ONCE).
// csrX / cscA store PRE-SHIFTED byte offsets (idx << 13 = idx * HH * 2B) for
// the gather kernels; csrA stores plain indices (consumed by k_s).
// ---------------------------------------------------------------------------
__global__ __launch_bounds__(256) void k_build(const float* __restrict__ x,
                                               unsigned* __restrict__ colfill,
                                               unsigned* __restrict__ degX,
                                               unsigned* __restrict__ degA,
                                               unsigned* __restrict__ csrX,
                                               unsigned* __restrict__ csrA,
                                               unsigned* __restrict__ cscA) {
    const int r = blockIdx.x;
    __shared__ unsigned px, pa;
    if (threadIdx.x == 0) { px = 0u; pa = 0u; }
    __syncthreads();
    const float4* xr = reinterpret_cast<const float4*>(x + (size_t)r * NN);
    #pragma unroll
    for (int i = 0; i < NN / (4 * 256); ++i) {
        const int c4 = i * 256 + threadIdx.x;
        float4 v = xr[c4];
        const float* vp = reinterpret_cast<const float*>(&v);
        #pragma unroll
        for (int k = 0; k < 4; ++k) {
            const int c = c4 * 4 + k;
            const bool nzx = (vp[k] != 0.0f);
            const bool nzA = nzx || (c == r);
            if (nzx) {
                unsigned p = atomicAdd(&px, 1u);
                if (p < STR) csrX[(size_t)r * STR + p] = (unsigned)c << 13;
            }
            if (nzA) {
                unsigned p = atomicAdd(&pa, 1u);
                if (p < STR) csrA[(size_t)r * STR + p] = (unsigned)c;
                unsigned q = atomicAdd(&colfill[c], 1u);
                if (q < STR) cscA[(size_t)c * STR + q] = (unsigned)r << 13;
            }
        }
    }
    __syncthreads();
    if (threadIdx.x == 0) { degX[r] = px; degA[r] = pa; }
}

// pooled adjacency + batch counts (dinv computed on the fly from colfill):
// s[g][r] = dinv[r] * sum_{c in rowA(r), batch[c]==g} dinv[c]
__global__ __launch_bounds__(256) void k_s(const unsigned* __restrict__ degA,
                                           const unsigned* __restrict__ csrA,
                                           const unsigned* __restrict__ colfill,
                                           const int* __restrict__ batch,
                                           float* __restrict__ s,
                                           unsigned* __restrict__ cnt) {
    const int r = blockIdx.x * 256 + threadIdx.x;
    atomicAdd(&cnt[batch[r]], 1u);
    unsigned deg = degA[r];
    if (deg > STR) deg = STR;
    float bins[GG];
    #pragma unroll
    for (int g = 0; g < GG; ++g) bins[g] = 0.0f;
    for (unsigned e = 0; e < deg; ++e) {
        const unsigned c = csrA[(size_t)r * STR + e];
        const float d = rsqrtf((float)colfill[c]);
        const int gb = batch[c];
        #pragma unroll
        for (int g = 0; g < GG; ++g) bins[g] += (gb == g) ? d : 0.0f;
    }
    const float dr = rsqrtf((float)colfill[r]);
    #pragma unroll
    for (int g = 0; g < GG; ++g) s[(size_t)g * NN + r] = dr * bins[g];
}

// ---------------------------------------------------------------------------
// Scalar-pipe gather SpMM1, 4-chunks-per-block. 1 wave = 1 node; the wave
// loops its XCD's chunk set {xcd, xcd+8, xcd+16, xcd+24}, reusing the
// K$-cached edge list. 64 lanes x 1 u32 (2 bf16) per edge per chunk.
// Mh[r, ch] = bf16( dinv[r] * sum_{c in csrX(r)} W1h[c, ch] )
// ---------------------------------------------------------------------------
__global__ __launch_bounds__(256) void k_spmm1(const char* __restrict__ W1b,
                                               const unsigned* __restrict__ degX,
                                               const unsigned* __restrict__ csrX,
                                               const unsigned* __restrict__ colfill,
                                               unsigned* __restrict__ Mh) {
    const unsigned L = blockIdx.x;
    const int xcd = L & 7;
    const int pix = L >> 3;
    int node = (pix << 2) | (threadIdx.x >> 6);
    node = __builtin_amdgcn_readfirstlane(node);
    const int lane = threadIdx.x & 63;

    unsigned deg = degX[node];
    if (deg > STR) deg = STR;
    const unsigned* __restrict__ el = csrX + (size_t)node * STR;  // uniform ptr
    const float dr = rsqrtf((float)colfill[node]);

    #pragma unroll
    for (int p = 0; p < 4; ++p) {
        const int ch = xcd + (p << 3);
        const unsigned loff = (unsigned)(ch * 64 + lane) * 4u;
        float2 acc = make_float2(0.f, 0.f);
        unsigned e = 0;
        for (; e + 8 <= deg; e += 8) {
            unsigned o0 = el[e + 0], o1 = el[e + 1], o2 = el[e + 2], o3 = el[e + 3];
            unsigned o4 = el[e + 4], o5 = el[e + 5], o6 = el[e + 6], o7 = el[e + 7];
            const unsigned v0 = *reinterpret_cast<const unsigned*>(W1b + (o0 + loff));
            const unsigned v1 = *reinterpret_cast<const unsigned*>(W1b + (o1 + loff));
            const unsigned v2 = *reinterpret_cast<const unsigned*>(W1b + (o2 + loff));
            const unsigned v3 = *reinterpret_cast<const unsigned*>(W1b + (o3 + loff));
            const unsigned v4 = *reinterpret_cast<const unsigned*>(W1b + (o4 + loff));
            const unsigned v5 = *reinterpret_cast<const unsigned*>(W1b + (o5 + loff));
            const unsigned v6 = *reinterpret_cast<const unsigned*>(W1b + (o6 + loff));
            const unsigned v7 = *reinterpret_cast<const unsigned*>(W1b + (o7 + loff));
            acc2p(acc, v0); acc2p(acc, v1); acc2p(acc, v2); acc2p(acc, v3);
            acc2p(acc, v4); acc2p(acc, v5); acc2p(acc, v6); acc2p(acc, v7);
        }
        for (; e < deg; ++e) {
            unsigned o = el[e];
            acc2p(acc, *reinterpret_cast<const unsigned*>(W1b + (o + loff)));
        }
        __builtin_nontemporal_store(pack2(dr * acc.x, dr * acc.y),
                                    &Mh[(size_t)node * (HH / 2) + ch * 64 + lane]);
    }
}

// ---------------------------------------------------------------------------
// Scalar-pipe gather conv1 (same structure):
// hB[c, ch] = bf16( relu(dinv[c]*sum_{rn in cscA(c)} Mh[rn,ch] + b1) )
// (Mh pre-scaled by dinv[rn].)
// ---------------------------------------------------------------------------
__global__ __launch_bounds__(256) void k_conv1(const char* __restrict__ Mb,
                                               const float* __restrict__ b1,
                                               const unsigned* __restrict__ colfill,
                                               const unsigned* __restrict__ cscA,
                                               unsigned* __restrict__ hB) {
    const unsigned L = blockIdx.x;
    const int xcd = L & 7;
    const int pix = L >> 3;
    int node = (pix << 2) | (threadIdx.x >> 6);
    node = __builtin_amdgcn_readfirstlane(node);
    const int lane = threadIdx.x & 63;

    unsigned deg = colfill[node];
    const float dc = rsqrtf((float)deg);
    if (deg > STR) deg = STR;
    const unsigned* __restrict__ el = cscA + (size_t)node * STR;  // uniform ptr

    #pragma unroll
    for (int p = 0; p < 4; ++p) {
        const int ch = xcd + (p << 3);
        const unsigned loff = (unsigned)(ch * 64 + lane) * 4u;
        float2 acc = make_float2(0.f, 0.f);
        unsigned e = 0;
        for (; e + 8 <= deg; e += 8) {
            unsigned o0 = el[e + 0], o1 = el[e + 1], o2 = el[e + 2], o3 = el[e + 3];
            unsigned o4 = el[e + 4], o5 = el[e + 5], o6 = el[e + 6], o7 = el[e + 7];
            const unsigned v0 = *reinterpret_cast<const unsigned*>(Mb + (o0 + loff));
            const unsigned v1 = *reinterpret_cast<const unsigned*>(Mb + (o1 + loff));
            const unsigned v2 = *reinterpret_cast<const unsigned*>(Mb + (o2 + loff));
            const unsigned v3 = *reinterpret_cast<const unsigned*>(Mb + (o3 + loff));
            const unsigned v4 = *reinterpret_cast<const unsigned*>(Mb + (o4 + loff));
            const unsigned v5 = *reinterpret_cast<const unsigned*>(Mb + (o5 + loff));
            const unsigned v6 = *reinterpret_cast<const unsigned*>(Mb + (o6 + loff));
            const unsigned v7 = *reinterpret_cast<const unsigned*>(Mb + (o7 + loff));
            acc2p(acc, v0); acc2p(acc, v1); acc2p(acc, v2); acc2p(acc, v3);
            acc2p(acc, v4); acc2p(acc, v5); acc2p(acc, v6); acc2p(acc, v7);
        }
        for (; e < deg; ++e) {
            unsigned o = el[e];
            acc2p(acc, *reinterpret_cast<const unsigned*>(Mb + (o + loff)));
        }
        const float2 bv = reinterpret_cast<const float2*>(b1)[ch * 64 + lane];
        const float h0 = fmaxf(fmaf(dc, acc.x, bv.x), 0.0f);
        const float h1 = fmaxf(fmaf(dc, acc.y, bv.y), 0.0f);
        __builtin_nontemporal_store(pack2(h0, h1),
                                    &hB[(size_t)node * (HH / 2) + ch * 64 + lane]);
    }
}

// ---------------------------------------------------------------------------
// Pool stage A: partial t per row-group, NO atomics.
// ---------------------------------------------------------------------------
__global__ __launch_bounds__(256) void k_poolA(const uint4* __restrict__ hB,
                                               const float* __restrict__ s,
                                               float* __restrict__ part) {
    const int j = blockIdx.x * 256 + threadIdx.x;      // uint4 col index
    const int c0 = blockIdx.y * (NN / PRG);            // 128 rows
    __shared__ float s_t[GG * (NN / PRG)];
    for (int i = threadIdx.x; i < GG * (NN / PRG); i += 256) {
        const int g = i / (NN / PRG);
        const int cc = i % (NN / PRG);
        s_t[i] = s[(size_t)g * NN + c0 + cc];
    }
    __syncthreads();
    float tacc[GG][8];
    #pragma unroll
    for (int g = 0; g < GG; ++g)
        #pragma unroll
        for (int q = 0; q < 8; ++q) tacc[g][q] = 0.0f;
    for (int cc = 0; cc < NN / PRG; ++cc) {
        const uint4 v = hB[(size_t)(c0 + cc) * (HH / 8) + j];
        float hv[8];
        unpack8(v, hv);
        #pragma unroll
        for (int g = 0; g < GG; ++g) {
            const float sv = s_t[g * (NN / PRG) + cc];
            #pragma unroll
            for (int q = 0; q < 8; ++q) tacc[g][q] = fmaf(sv, hv[q], tacc[g][q]);
        }
    }
    float4* p4 = reinterpret_cast<float4*>(part);
    #pragma unroll
    for (int g = 0; g < GG; ++g) {
        const size_t base = ((size_t)(blockIdx.y * GG + g) * HH) / 4 + j * 2;
        p4[base]     = make_float4(tacc[g][0], tacc[g][1], tacc[g][2], tacc[g][3]);
        p4[base + 1] = make_float4(tacc[g][4], tacc[g][5], tacc[g][6], tacc[g][7]);
    }
}

// Pool stage B: t[g][j] = sum_rg part[rg][g][j]
__global__ __launch_bounds__(256) void k_poolB(const float* __restrict__ part,
                                               float* __restrict__ t) {
    const int idx = blockIdx.x * 256 + threadIdx.x;    // float4 index into t
    const int g = idx / (HH / 4);
    const int j4 = idx % (HH / 4);
    const float4* p4 = reinterpret_cast<const float4*>(part);
    float4 acc = make_float4(0.f, 0.f, 0.f, 0.f);
    for (int rg = 0; rg < PRG; ++rg) {
        const float4 v = p4[((size_t)(rg * GG + g) * HH) / 4 + j4];
        acc.x += v.x; acc.y += v.y; acc.z += v.z; acc.w += v.w;
    }
    reinterpret_cast<float4*>(t)[idx] = acc;
}

// ---------------------------------------------------------------------------
// Final stage A: part2[jg][g][n] = sum_{j in jgroup} (t[g,j]/cnt[g]) * W2[j,n]
// ---------------------------------------------------------------------------
__global__ __launch_bounds__(256) void k_final(const float* __restrict__ W2,
                                               const float* __restrict__ t,
                                               const unsigned* __restrict__ cnt,
                                               float* __restrict__ part2) {
    __shared__ float tld[GG * 128];
    const int tj = threadIdx.x;
    const int j0 = blockIdx.y * 128;
    const int nbase = blockIdx.x * 1024;
    for (int i = threadIdx.x; i < GG * 128; i += 256) {
        const int g = i >> 7;
        const int jj = i & 127;
        unsigned c = cnt[g];
        if (c < 1u) c = 1u;
        tld[i] = t[(size_t)g * HH + j0 + jj] * (1.0f / (float)c);
    }
    __syncthreads();
    float4 acc[GG];
    #pragma unroll
    for (int g = 0; g < GG; ++g) acc[g] = make_float4(0.f, 0.f, 0.f, 0.f);
    for (int jj = 0; jj < 128; ++jj) {
        const int jv = j0 + jj;
        float4 w = reinterpret_cast<const float4*>(W2 + (size_t)jv * NN + nbase)[tj];
        #pragma unroll
        for (int g = 0; g < GG; ++g) {
            const float tv = tld[g * 128 + jj];
            acc[g].x = fmaf(tv, w.x, acc[g].x);
            acc[g].y = fmaf(tv, w.y, acc[g].y);
            acc[g].z = fmaf(tv, w.z, acc[g].z);
            acc[g].w = fmaf(tv, w.w, acc[g].w);
        }
    }
    float4* p4 = reinterpret_cast<float4*>(part2);
    #pragma unroll
    for (int g = 0; g < GG; ++g)
        p4[((size_t)(blockIdx.y * GG + g) * NN + nbase) / 4 + tj] = acc[g];
}

// Final stage B: out[g][n] = b2[n] + sum_jg part2[jg][g][n]
__global__ __launch_bounds__(256) void k_fin2(const float* __restrict__ part2,
                                              const float* __restrict__ b2,
                                              float* __restrict__ out) {
    const int idx = blockIdx.x * 256 + threadIdx.x;    // float4 index into out
    const int g = idx / (NN / 4);
    const int n4 = idx % (NN / 4);
    const float4* p4 = reinterpret_cast<const float4*>(part2);
    float4 acc = reinterpret_cast<const float4*>(b2)[n4];
    for (int jg = 0; jg < FJG; ++jg) {
        const float4 v = p4[((size_t)(jg * GG + g) * NN) / 4 + n4];
        acc.x += v.x; acc.y += v.y; acc.z += v.z; acc.w += v.w;
    }
    reinterpret_cast<float4*>(out)[idx] = acc;
}

extern "C" void kernel_launch(void* const* d_in, const int* in_sizes, int n_in,
                              void* d_out, int out_size, void* d_ws, size_t ws_size,
                              hipStream_t stream) {
    const float* x  = (const float*)d_in[0];
    const float* W1 = (const float*)d_in[1];
    const float* b1 = (const float*)d_in[2];
    const float* W2 = (const float*)d_in[3];
    const float* b2 = (const float*)d_in[4];
    const int* batch = (const int*)d_in[5];
    float* out = (float*)d_out;

    char* ws = (char*)d_ws;
    size_t off = 0;
    auto alloc = [&](size_t bytes) -> char* {
        char* p = ws + off;
        off = (off + bytes + 255) & ~(size_t)255;
        return p;
    };
    uint4*    Mh      = (uint4*)   alloc((size_t)NN * HH * 2);   // bf16 M (dinv-scaled)
    uint4*    W1h     = (uint4*)   alloc((size_t)NN * HH * 2);   // bf16 W1; REUSED as hB
    uint4*    hB      = W1h;   // h overlays W1h (dead after k_spmm1; stream-serial)
    char*     zbegin  = ws + off;
    float*    t       = (float*)   alloc((size_t)GG * HH * 4);
    unsigned* colfill = (unsigned*)alloc((size_t)NN * 4);
    unsigned* cnt     = (unsigned*)alloc((size_t)GG * 4);
    char*     zend    = ws + off;
    float*    s       = (float*)   alloc((size_t)GG * NN * 4);
    unsigned* degX    = (unsigned*)alloc((size_t)NN * 4);
    unsigned* degA    = (unsigned*)alloc((size_t)NN * 4);
    unsigned* csrX    = (unsigned*)alloc((size_t)NN * STR * 4);  // 4 MB
    unsigned* csrA    = (unsigned*)alloc((size_t)NN * STR * 4);  // 4 MB (contiguous)
    unsigned* cscA    = (unsigned*)alloc((size_t)NN * STR * 4);
    // part (poolA->poolB, 8 MB) and part2 (final->fin2, 8 MB) overlay the
    // csrX+csrA region (dead by then; stream-serial).
    float*    part    = (float*)csrX;
    float*    part2   = (float*)csrX;
    (void)ws_size; (void)in_sizes; (void)n_in; (void)out_size;

    hipMemsetAsync(zbegin, 0, (size_t)(zend - zbegin), stream);

    k_cvt<<<(NN * HH / 8) / 256, 256, 0, stream>>>(W1, (uint4*)W1h);
    k_build<<<NN, 256, 0, stream>>>(x, colfill, degX, degA, csrX, csrA, cscA);
    k_s<<<NN / 256, 256, 0, stream>>>(degA, csrA, colfill, batch, s, cnt);
    k_spmm1<<<(NN / 4) * 8, 256, 0, stream>>>((const char*)W1h, degX, csrX, colfill,
                                              (unsigned*)Mh);
    k_conv1<<<(NN / 4) * 8, 256, 0, stream>>>((const char*)Mh, b1, colfill, cscA,
                                              (unsigned*)hB);
    k_poolA<<<dim3(HH / 2048, PRG), 256, 0, stream>>>(hB, s, part);
    k_poolB<<<(GG * HH / 4) / 256, 256, 0, stream>>>(part, t);
    k_final<<<dim3(NN / 1024, FJG), 256, 0, stream>>>(W2, t, cnt, part2);
    k_fin2<<<(GG * NN / 4) / 256, 256, 0, stream>>>(part2, b2, out);
}

// Round 14
// 626.548 us; speedup vs baseline: 1.1073x; 1.1073x over previous
//
#include <hip/hip_runtime.h>
#include <hip/hip_bf16.h>

#define NN 8192
#define HH 4096
#define GG 8
#define STR 128            // fixed stride for per-node edge lists (max deg ~57)
#define NCH 32             // H chunks (128 cols = 2 MB/chunk in bf16)
#define PRG 64             // pool row-groups (partial-reduction factor)
#define FJG 32             // final j-groups

typedef unsigned uint4n __attribute__((ext_vector_type(4)));  // native vec for NT stores

// ---------------------------------------------------------------------------
// bf16 helpers (packed 2x bf16 per u32; element 2q in low 16 bits)
// ---------------------------------------------------------------------------
__device__ inline unsigned bf16rne(float f) {
    unsigned u = __float_as_uint(f);
    unsigned r = 0x7fffu + ((u >> 16) & 1u);
    return (u + r) >> 16;
}
__device__ inline unsigned pack2(float lo, float hi) {
    return bf16rne(lo) | (bf16rne(hi) << 16);
}
__device__ inline void nt_store16(void* p, unsigned a, unsigned b, unsigned c, unsigned d) {
    uint4n v; v.x = a; v.y = b; v.z = c; v.w = d;
    __builtin_nontemporal_store(v, reinterpret_cast<uint4n*>(p));
}
// acc (2 elems) += unpacked u32 via packed add
__device__ inline void acc2p(float2& acc, unsigned u) {
    float2 t;
    t.x = __uint_as_float(u << 16);
    t.y = __uint_as_float(u & 0xffff0000u);
    asm("v_pk_add_f32 %0, %1, %0" : "+v"(acc) : "v"(t));
}
__device__ inline void unpack8(uint4 v, float* __restrict__ h) {
    const unsigned* pu = reinterpret_cast<const unsigned*>(&v);
    #pragma unroll
    for (int q = 0; q < 4; ++q) {
        const unsigned u = pu[q];
        h[2 * q]     = __uint_as_float(u << 16);
        h[2 * q + 1] = __uint_as_float(u & 0xffff0000u);
    }
}

// ---------------------------------------------------------------------------
// Fused front kernel. Blocks [0, NN): single-pass graph build (reads x once).
// Blocks [NN, NN + NN*HH/8/256): W1 fp32 -> bf16 convert (NT stores).
// Independent work co-resident -> overlapped HBM traffic, one less launch.
// csrX / cscA store PRE-SHIFTED byte offsets (idx << 13 = idx * HH * 2B);
// csrA stores plain indices (consumed by k_s).
// ---------------------------------------------------------------------------
__global__ __launch_bounds__(256) void k_front(const float* __restrict__ x,
                                               const float* __restrict__ W1,
                                               uint4* __restrict__ W1h,
                                               unsigned* __restrict__ colfill,
                                               unsigned* __restrict__ degX,
                                               unsigned* __restrict__ degA,
                                               unsigned* __restrict__ csrX,
                                               unsigned* __restrict__ csrA,
                                               unsigned* __restrict__ cscA) {
    __shared__ unsigned px, pa;
    const int bid = blockIdx.x;
    if (bid >= NN) {
        // ---- cvt part ----
        const size_t i = (size_t)(bid - NN) * 256 + threadIdx.x;
        const float4 a = reinterpret_cast<const float4*>(W1)[2 * i];
        const float4 b = reinterpret_cast<const float4*>(W1)[2 * i + 1];
        nt_store16(&W1h[i], pack2(a.x, a.y), pack2(a.z, a.w),
                            pack2(b.x, b.y), pack2(b.z, b.w));
        return;
    }
    // ---- build part: row bid ----
    const int r = bid;
    if (threadIdx.x == 0) { px = 0u; pa = 0u; }
    __syncthreads();
    const float4* xr = reinterpret_cast<const float4*>(x + (size_t)r * NN);
    #pragma unroll
    for (int i = 0; i < NN / (4 * 256); ++i) {
        const int c4 = i * 256 + threadIdx.x;
        float4 v = xr[c4];
        const float* vp = reinterpret_cast<const float*>(&v);
        #pragma unroll
        for (int k = 0; k < 4; ++k) {
            const int c = c4 * 4 + k;
            const bool nzx = (vp[k] != 0.0f);
            const bool nzA = nzx || (c == r);
            if (nzx) {
                unsigned p = atomicAdd(&px, 1u);
                if (p < STR) csrX[(size_t)r * STR + p] = (unsigned)c << 13;
            }
            if (nzA) {
                unsigned p = atomicAdd(&pa, 1u);
                if (p < STR) csrA[(size_t)r * STR + p] = (unsigned)c;
                unsigned q = atomicAdd(&colfill[c], 1u);
                if (q < STR) cscA[(size_t)c * STR + q] = (unsigned)r << 13;
            }
        }
    }
    __syncthreads();
    if (threadIdx.x == 0) { degX[r] = px; degA[r] = pa; }
}

// pooled adjacency + batch counts (dinv computed on the fly from colfill):
// s[g][r] = dinv[r] * sum_{c in rowA(r), batch[c]==g} dinv[c]
__global__ __launch_bounds__(256) void k_s(const unsigned* __restrict__ degA,
                                           const unsigned* __restrict__ csrA,
                                           const unsigned* __restrict__ colfill,
                                           const int* __restrict__ batch,
                                           float* __restrict__ s,
                                           unsigned* __restrict__ cnt) {
    const int r = blockIdx.x * 256 + threadIdx.x;
    atomicAdd(&cnt[batch[r]], 1u);
    unsigned deg = degA[r];
    if (deg > STR) deg = STR;
    float bins[GG];
    #pragma unroll
    for (int g = 0; g < GG; ++g) bins[g] = 0.0f;
    for (unsigned e = 0; e < deg; ++e) {
        const unsigned c = csrA[(size_t)r * STR + e];
        const float d = rsqrtf((float)colfill[c]);
        const int gb = batch[c];
        #pragma unroll
        for (int g = 0; g < GG; ++g) bins[g] += (gb == g) ? d : 0.0f;
    }
    const float dr = rsqrtf((float)colfill[r]);
    #pragma unroll
    for (int g = 0; g < GG; ++g) s[(size_t)g * NN + r] = dr * bins[g];
}

// ---------------------------------------------------------------------------
// Scalar-pipe gather SpMM1 (r12 structure — proven floor). 1 wave = 1
// (node, 128-col chunk); 64 lanes x 1 u32 (2 bf16). Edge list wave-uniform
// (readfirstlane -> s_load offsets). XCD-pinned chunks; NT result store.
// Mh[r, ch] = bf16( dinv[r] * sum_{c in csrX(r)} W1h[c, ch] )
// ---------------------------------------------------------------------------
__global__ __launch_bounds__(256) void k_spmm1(const char* __restrict__ W1b,
                                               const unsigned* __restrict__ degX,
                                               const unsigned* __restrict__ csrX,
                                               const unsigned* __restrict__ colfill,
                                               unsigned* __restrict__ Mh) {
    const unsigned L = blockIdx.x;
    const int xcd   = L & 7;
    const unsigned k = L >> 3;
    const int phase = k >> 11;            // 2048 node-quads per phase
    const int pix   = k & 2047;
    const int ch    = xcd + (phase << 3); // this XCD's chunk set {x, x+8, x+16, x+24}
    int node = (pix << 2) | (threadIdx.x >> 6);
    node = __builtin_amdgcn_readfirstlane(node);
    const int lane = threadIdx.x & 63;

    unsigned deg = degX[node];
    if (deg > STR) deg = STR;
    const unsigned* __restrict__ el = csrX + (size_t)node * STR;  // uniform ptr
    const unsigned loff = (unsigned)(ch * 64 + lane) * 4u;

    float2 acc = make_float2(0.f, 0.f);
    unsigned e = 0;
    for (; e + 8 <= deg; e += 8) {
        unsigned o0 = el[e + 0], o1 = el[e + 1], o2 = el[e + 2], o3 = el[e + 3];
        unsigned o4 = el[e + 4], o5 = el[e + 5], o6 = el[e + 6], o7 = el[e + 7];
        const unsigned v0 = *reinterpret_cast<const unsigned*>(W1b + (o0 + loff));
        const unsigned v1 = *reinterpret_cast<const unsigned*>(W1b + (o1 + loff));
        const unsigned v2 = *reinterpret_cast<const unsigned*>(W1b + (o2 + loff));
        const unsigned v3 = *reinterpret_cast<const unsigned*>(W1b + (o3 + loff));
        const unsigned v4 = *reinterpret_cast<const unsigned*>(W1b + (o4 + loff));
        const unsigned v5 = *reinterpret_cast<const unsigned*>(W1b + (o5 + loff));
        const unsigned v6 = *reinterpret_cast<const unsigned*>(W1b + (o6 + loff));
        const unsigned v7 = *reinterpret_cast<const unsigned*>(W1b + (o7 + loff));
        acc2p(acc, v0); acc2p(acc, v1); acc2p(acc, v2); acc2p(acc, v3);
        acc2p(acc, v4); acc2p(acc, v5); acc2p(acc, v6); acc2p(acc, v7);
    }
    for (; e < deg; ++e) {
        unsigned o = el[e];
        acc2p(acc, *reinterpret_cast<const unsigned*>(W1b + (o + loff)));
    }

    const float dr = rsqrtf((float)colfill[node]);
    __builtin_nontemporal_store(pack2(dr * acc.x, dr * acc.y),
                                &Mh[(size_t)node * (HH / 2) + ch * 64 + lane]);
}

// ---------------------------------------------------------------------------
// Scalar-pipe gather conv1 (same structure):
// hB[c, ch] = bf16( relu(dinv[c]*sum_{rn in cscA(c)} Mh[rn,ch] + b1) )
// (Mh pre-scaled by dinv[rn].)
// ---------------------------------------------------------------------------
__global__ __launch_bounds__(256) void k_conv1(const char* __restrict__ Mb,
                                               const float* __restrict__ b1,
                                               const unsigned* __restrict__ colfill,
                                               const unsigned* __restrict__ cscA,
                                               unsigned* __restrict__ hB) {
    const unsigned L = blockIdx.x;
    const int xcd   = L & 7;
    const unsigned k = L >> 3;
    const int phase = k >> 11;
    const int pix   = k & 2047;
    const int ch    = xcd + (phase << 3);
    int node = (pix << 2) | (threadIdx.x >> 6);
    node = __builtin_amdgcn_readfirstlane(node);
    const int lane = threadIdx.x & 63;

    unsigned deg = colfill[node];
    const float dc = rsqrtf((float)deg);
    if (deg > STR) deg = STR;
    const unsigned* __restrict__ el = cscA + (size_t)node * STR;  // uniform ptr
    const unsigned loff = (unsigned)(ch * 64 + lane) * 4u;

    float2 acc = make_float2(0.f, 0.f);
    unsigned e = 0;
    for (; e + 8 <= deg; e += 8) {
        unsigned o0 = el[e + 0], o1 = el[e + 1], o2 = el[e + 2], o3 = el[e + 3];
        unsigned o4 = el[e + 4], o5 = el[e + 5], o6 = el[e + 6], o7 = el[e + 7];
        const unsigned v0 = *reinterpret_cast<const unsigned*>(Mb + (o0 + loff));
        const unsigned v1 = *reinterpret_cast<const unsigned*>(Mb + (o1 + loff));
        const unsigned v2 = *reinterpret_cast<const unsigned*>(Mb + (o2 + loff));
        const unsigned v3 = *reinterpret_cast<const unsigned*>(Mb + (o3 + loff));
        const unsigned v4 = *reinterpret_cast<const unsigned*>(Mb + (o4 + loff));
        const unsigned v5 = *reinterpret_cast<const unsigned*>(Mb + (o5 + loff));
        const unsigned v6 = *reinterpret_cast<const unsigned*>(Mb + (o6 + loff));
        const unsigned v7 = *reinterpret_cast<const unsigned*>(Mb + (o7 + loff));
        acc2p(acc, v0); acc2p(acc, v1); acc2p(acc, v2); acc2p(acc, v3);
        acc2p(acc, v4); acc2p(acc, v5); acc2p(acc, v6); acc2p(acc, v7);
    }
    for (; e < deg; ++e) {
        unsigned o = el[e];
        acc2p(acc, *reinterpret_cast<const unsigned*>(Mb + (o + loff)));
    }

    const float2 bv = reinterpret_cast<const float2*>(b1)[ch * 64 + lane];
    const float h0 = fmaxf(fmaf(dc, acc.x, bv.x), 0.0f);
    const float h1 = fmaxf(fmaf(dc, acc.y, bv.y), 0.0f);
    __builtin_nontemporal_store(pack2(h0, h1),
                                &hB[(size_t)node * (HH / 2) + ch * 64 + lane]);
}

// ---------------------------------------------------------------------------
// Pool stage A: partial t per row-group, NO atomics.
// ---------------------------------------------------------------------------
__global__ __launch_bounds__(256) void k_poolA(const uint4* __restrict__ hB,
                                               const float* __restrict__ s,
                                               float* __restrict__ part) {
    const int j = blockIdx.x * 256 + threadIdx.x;      // uint4 col index
    const int c0 = blockIdx.y * (NN / PRG);            // 128 rows
    __shared__ float s_t[GG * (NN / PRG)];
    for (int i = threadIdx.x; i < GG * (NN / PRG); i += 256) {
        const int g = i / (NN / PRG);
        const int cc = i % (NN / PRG);
        s_t[i] = s[(size_t)g * NN + c0 + cc];
    }
    __syncthreads();
    float tacc[GG][8];
    #pragma unroll
    for (int g = 0; g < GG; ++g)
        #pragma unroll
        for (int q = 0; q < 8; ++q) tacc[g][q] = 0.0f;
    for (int cc = 0; cc < NN / PRG; ++cc) {
        const uint4 v = hB[(size_t)(c0 + cc) * (HH / 8) + j];
        float hv[8];
        unpack8(v, hv);
        #pragma unroll
        for (int g = 0; g < GG; ++g) {
            const float sv = s_t[g * (NN / PRG) + cc];
            #pragma unroll
            for (int q = 0; q < 8; ++q) tacc[g][q] = fmaf(sv, hv[q], tacc[g][q]);
        }
    }
    float4* p4 = reinterpret_cast<float4*>(part);
    #pragma unroll
    for (int g = 0; g < GG; ++g) {
        const size_t base = ((size_t)(blockIdx.y * GG + g) * HH) / 4 + j * 2;
        p4[base]     = make_float4(tacc[g][0], tacc[g][1], tacc[g][2], tacc[g][3]);
        p4[base + 1] = make_float4(tacc[g][4], tacc[g][5], tacc[g][6], tacc[g][7]);
    }
}

// Pool stage B: t[g][j] = sum_rg part[rg][g][j]
__global__ __launch_bounds__(256) void k_poolB(const float* __restrict__ part,
                                               float* __restrict__ t) {
    const int idx = blockIdx.x * 256 + threadIdx.x;    // float4 index into t
    const int g = idx / (HH / 4);
    const int j4 = idx % (HH / 4);
    const float4* p4 = reinterpret_cast<const float4*>(part);
    float4 acc = make_float4(0.f, 0.f, 0.f, 0.f);
    for (int rg = 0; rg < PRG; ++rg) {
        const float4 v = p4[((size_t)(rg * GG + g) * HH) / 4 + j4];
        acc.x += v.x; acc.y += v.y; acc.z += v.z; acc.w += v.w;
    }
    reinterpret_cast<float4*>(t)[idx] = acc;
}

// ---------------------------------------------------------------------------
// Final stage A: part2[jg][g][n] = sum_{j in jgroup} (t[g,j]/cnt[g]) * W2[j,n]
// ---------------------------------------------------------------------------
__global__ __launch_bounds__(256) void k_final(const float* __restrict__ W2,
                                               const float* __restrict__ t,
                                               const unsigned* __restrict__ cnt,
                                               float* __restrict__ part2) {
    __shared__ float tld[GG * 128];
    const int tj = threadIdx.x;
    const int j0 = blockIdx.y * 128;
    const int nbase = blockIdx.x * 1024;
    for (int i = threadIdx.x; i < GG * 128; i += 256) {
        const int g = i >> 7;
        const int jj = i & 127;
        unsigned c = cnt[g];
        if (c < 1u) c = 1u;
        tld[i] = t[(size_t)g * HH + j0 + jj] * (1.0f / (float)c);
    }
    __syncthreads();
    float4 acc[GG];
    #pragma unroll
    for (int g = 0; g < GG; ++g) acc[g] = make_float4(0.f, 0.f, 0.f, 0.f);
    for (int jj = 0; jj < 128; ++jj) {
        const int jv = j0 + jj;
        float4 w = reinterpret_cast<const float4*>(W2 + (size_t)jv * NN + nbase)[tj];
        #pragma unroll
        for (int g = 0; g < GG; ++g) {
            const float tv = tld[g * 128 + jj];
            acc[g].x = fmaf(tv, w.x, acc[g].x);
            acc[g].y = fmaf(tv, w.y, acc[g].y);
            acc[g].z = fmaf(tv, w.z, acc[g].z);
            acc[g].w = fmaf(tv, w.w, acc[g].w);
        }
    }
    float4* p4 = reinterpret_cast<float4*>(part2);
    #pragma unroll
    for (int g = 0; g < GG; ++g)
        p4[((size_t)(blockIdx.y * GG + g) * NN + nbase) / 4 + tj] = acc[g];
}

// Final stage B: out[g][n] = b2[n] + sum_jg part2[jg][g][n]
__global__ __launch_bounds__(256) void k_fin2(const float* __restrict__ part2,
                                              const float* __restrict__ b2,
                                              float* __restrict__ out) {
    const int idx = blockIdx.x * 256 + threadIdx.x;    // float4 index into out
    const int g = idx / (NN / 4);
    const int n4 = idx % (NN / 4);
    const float4* p4 = reinterpret_cast<const float4*>(part2);
    float4 acc = reinterpret_cast<const float4*>(b2)[n4];
    for (int jg = 0; jg < FJG; ++jg) {
        const float4 v = p4[((size_t)(jg * GG + g) * NN) / 4 + n4];
        acc.x += v.x; acc.y += v.y; acc.z += v.z; acc.w += v.w;
    }
    reinterpret_cast<float4*>(out)[idx] = acc;
}

extern "C" void kernel_launch(void* const* d_in, const int* in_sizes, int n_in,
                              void* d_out, int out_size, void* d_ws, size_t ws_size,
                              hipStream_t stream) {
    const float* x  = (const float*)d_in[0];
    const float* W1 = (const float*)d_in[1];
    const float* b1 = (const float*)d_in[2];
    const float* W2 = (const float*)d_in[3];
    const float* b2 = (const float*)d_in[4];
    const int* batch = (const int*)d_in[5];
    float* out = (float*)d_out;

    char* ws = (char*)d_ws;
    size_t off = 0;
    auto alloc = [&](size_t bytes) -> char* {
        char* p = ws + off;
        off = (off + bytes + 255) & ~(size_t)255;
        return p;
    };
    uint4*    Mh      = (uint4*)   alloc((size_t)NN * HH * 2);   // bf16 M (dinv-scaled)
    uint4*    W1h     = (uint4*)   alloc((size_t)NN * HH * 2);   // bf16 W1; REUSED as hB
    uint4*    hB      = W1h;   // h overlays W1h (dead after k_spmm1; stream-serial)
    char*     zbegin  = ws + off;
    float*    t       = (float*)   alloc((size_t)GG * HH * 4);
    unsigned* colfill = (unsigned*)alloc((size_t)NN * 4);
    unsigned* cnt     = (unsigned*)alloc((size_t)GG * 4);
    char*     zend    = ws + off;
    float*    s       = (float*)   alloc((size_t)GG * NN * 4);
    unsigned* degX    = (unsigned*)alloc((size_t)NN * 4);
    unsigned* degA    = (unsigned*)alloc((size_t)NN * 4);
    unsigned* csrX    = (unsigned*)alloc((size_t)NN * STR * 4);  // 4 MB
    unsigned* csrA    = (unsigned*)alloc((size_t)NN * STR * 4);  // 4 MB (contiguous)
    unsigned* cscA    = (unsigned*)alloc((size_t)NN * STR * 4);
    // part (poolA->poolB, 8 MB) and part2 (final->fin2, 8 MB) overlay the
    // csrX+csrA region (dead by then; stream-serial).
    float*    part    = (float*)csrX;
    float*    part2   = (float*)csrX;
    (void)ws_size; (void)in_sizes; (void)n_in; (void)out_size;

    hipMemsetAsync(zbegin, 0, (size_t)(zend - zbegin), stream);

    k_front<<<NN + (NN * HH / 8) / 256, 256, 0, stream>>>(x, W1, (uint4*)W1h, colfill,
                                                          degX, degA, csrX, csrA, cscA);
    k_s<<<NN / 256, 256, 0, stream>>>(degA, csrA, colfill, batch, s, cnt);
    k_spmm1<<<(NN / 4) * NCH, 256, 0, stream>>>((const char*)W1h, degX, csrX, colfill,
                                                (unsigned*)Mh);
    k_conv1<<<(NN / 4) * NCH, 256, 0, stream>>>((const char*)Mh, b1, colfill, cscA,
                                                (unsigned*)hB);
    k_poolA<<<dim3(HH / 2048, PRG), 256, 0, stream>>>(hB, s, part);
    k_poolB<<<(GG * HH / 4) / 256, 256, 0, stream>>>(part, t);
    k_final<<<dim3(NN / 1024, FJG), 256, 0, stream>>>(W2, t, cnt, part2);
    k_fin2<<<(GG * NN / 4) / 256, 256, 0, stream>>>(part2, b2, out);
}

// Round 15
// 597.842 us; speedup vs baseline: 1.1605x; 1.0480x over previous
//
#include <hip/hip_runtime.h>
#include <hip/hip_bf16.h>

#define NN 8192
#define HH 4096
#define GG 8
#define STR 128            // fixed stride for per-node edge lists (max deg ~57)
#define NCH 32             // H chunks (128 cols = 2 MB/chunk in bf16)
#define PRG 256            // pool row-groups (32 rows each) -> 512 blocks
#define FJG 64             // final j-groups (64 j each)     -> 512 blocks

typedef unsigned uint4n __attribute__((ext_vector_type(4)));  // native vec for NT stores

// ---------------------------------------------------------------------------
// bf16 helpers (packed 2x bf16 per u32; element 2q in low 16 bits)
// ---------------------------------------------------------------------------
__device__ inline unsigned bf16rne(float f) {
    unsigned u = __float_as_uint(f);
    unsigned r = 0x7fffu + ((u >> 16) & 1u);
    return (u + r) >> 16;
}
__device__ inline unsigned pack2(float lo, float hi) {
    return bf16rne(lo) | (bf16rne(hi) << 16);
}
__device__ inline void nt_store16(void* p, unsigned a, unsigned b, unsigned c, unsigned d) {
    uint4n v; v.x = a; v.y = b; v.z = c; v.w = d;
    __builtin_nontemporal_store(v, reinterpret_cast<uint4n*>(p));
}
// acc (2 elems) += unpacked u32 via packed add
__device__ inline void acc2p(float2& acc, unsigned u) {
    float2 t;
    t.x = __uint_as_float(u << 16);
    t.y = __uint_as_float(u & 0xffff0000u);
    asm("v_pk_add_f32 %0, %1, %0" : "+v"(acc) : "v"(t));
}
__device__ inline void unpack8(uint4 v, float* __restrict__ h) {
    const unsigned* pu = reinterpret_cast<const unsigned*>(&v);
    #pragma unroll
    for (int q = 0; q < 4; ++q) {
        const unsigned u = pu[q];
        h[2 * q]     = __uint_as_float(u << 16);
        h[2 * q + 1] = __uint_as_float(u & 0xffff0000u);
    }
}

// ---------------------------------------------------------------------------
// Fused front kernel. Blocks [0, NN): single-pass graph build (reads x once,
// with all-zero float4 fast path — x is 99.6% zeros). Blocks [NN, ...): W1
// fp32 -> bf16 convert (NT stores).
// csrX / cscA store PRE-SHIFTED byte offsets (idx << 13 = idx * HH * 2B);
// csrA stores plain indices (consumed by k_s).
// ---------------------------------------------------------------------------
__global__ __launch_bounds__(256) void k_front(const float* __restrict__ x,
                                               const float* __restrict__ W1,
                                               uint4* __restrict__ W1h,
                                               unsigned* __restrict__ colfill,
                                               unsigned* __restrict__ degX,
                                               unsigned* __restrict__ degA,
                                               unsigned* __restrict__ csrX,
                                               unsigned* __restrict__ csrA,
                                               unsigned* __restrict__ cscA) {
    __shared__ unsigned px, pa;
    const int bid = blockIdx.x;
    if (bid >= NN) {
        // ---- cvt part ----
        const size_t i = (size_t)(bid - NN) * 256 + threadIdx.x;
        const float4 a = reinterpret_cast<const float4*>(W1)[2 * i];
        const float4 b = reinterpret_cast<const float4*>(W1)[2 * i + 1];
        nt_store16(&W1h[i], pack2(a.x, a.y), pack2(a.z, a.w),
                            pack2(b.x, b.y), pack2(b.z, b.w));
        return;
    }
    // ---- build part: row bid ----
    const int r = bid;
    const int rq = r >> 2;                  // quad index containing the diagonal
    if (threadIdx.x == 0) { px = 0u; pa = 0u; }
    __syncthreads();
    const float4* xr = reinterpret_cast<const float4*>(x + (size_t)r * NN);
    #pragma unroll
    for (int i = 0; i < NN / (4 * 256); ++i) {
        const int c4 = i * 256 + threadIdx.x;
        float4 v = xr[c4];
        const bool any = (v.x != 0.0f) || (v.y != 0.0f) || (v.z != 0.0f) || (v.w != 0.0f);
        if (!any && (c4 != rq)) continue;   // fast path: ~99% of quads
        const float* vp = reinterpret_cast<const float*>(&v);
        #pragma unroll
        for (int k = 0; k < 4; ++k) {
            const int c = c4 * 4 + k;
            const bool nzx = (vp[k] != 0.0f);
            const bool nzA = nzx || (c == r);
            if (nzx) {
                unsigned p = atomicAdd(&px, 1u);
                if (p < STR) csrX[(size_t)r * STR + p] = (unsigned)c << 13;
            }
            if (nzA) {
                unsigned p = atomicAdd(&pa, 1u);
                if (p < STR) csrA[(size_t)r * STR + p] = (unsigned)c;
                unsigned q = atomicAdd(&colfill[c], 1u);
                if (q < STR) cscA[(size_t)c * STR + q] = (unsigned)r << 13;
            }
        }
    }
    __syncthreads();
    if (threadIdx.x == 0) { degX[r] = px; degA[r] = pa; }
}

// pooled adjacency + batch counts (dinv computed on the fly from colfill):
// s[g][r] = dinv[r] * sum_{c in rowA(r), batch[c]==g} dinv[c]
__global__ __launch_bounds__(256) void k_s(const unsigned* __restrict__ degA,
                                           const unsigned* __restrict__ csrA,
                                           const unsigned* __restrict__ colfill,
                                           const int* __restrict__ batch,
                                           float* __restrict__ s,
                                           unsigned* __restrict__ cnt) {
    const int r = blockIdx.x * 256 + threadIdx.x;
    atomicAdd(&cnt[batch[r]], 1u);
    unsigned deg = degA[r];
    if (deg > STR) deg = STR;
    float bins[GG];
    #pragma unroll
    for (int g = 0; g < GG; ++g) bins[g] = 0.0f;
    for (unsigned e = 0; e < deg; ++e) {
        const unsigned c = csrA[(size_t)r * STR + e];
        const float d = rsqrtf((float)colfill[c]);
        const int gb = batch[c];
        #pragma unroll
        for (int g = 0; g < GG; ++g) bins[g] += (gb == g) ? d : 0.0f;
    }
    const float dr = rsqrtf((float)colfill[r]);
    #pragma unroll
    for (int g = 0; g < GG; ++g) s[(size_t)g * NN + r] = dr * bins[g];
}

// ---------------------------------------------------------------------------
// Scalar-pipe gather SpMM1 (r12 structure — proven floor). 1 wave = 1
// (node, 128-col chunk); 64 lanes x 1 u32 (2 bf16). Edge list wave-uniform
// (readfirstlane -> s_load offsets). XCD-pinned chunks; NT result store.
// Mh[r, ch] = bf16( dinv[r] * sum_{c in csrX(r)} W1h[c, ch] )
// ---------------------------------------------------------------------------
__global__ __launch_bounds__(256) void k_spmm1(const char* __restrict__ W1b,
                                               const unsigned* __restrict__ degX,
                                               const unsigned* __restrict__ csrX,
                                               const unsigned* __restrict__ colfill,
                                               unsigned* __restrict__ Mh) {
    const unsigned L = blockIdx.x;
    const int xcd   = L & 7;
    const unsigned k = L >> 3;
    const int phase = k >> 11;            // 2048 node-quads per phase
    const int pix   = k & 2047;
    const int ch    = xcd + (phase << 3); // this XCD's chunk set {x, x+8, x+16, x+24}
    int node = (pix << 2) | (threadIdx.x >> 6);
    node = __builtin_amdgcn_readfirstlane(node);
    const int lane = threadIdx.x & 63;

    unsigned deg = degX[node];
    if (deg > STR) deg = STR;
    const unsigned* __restrict__ el = csrX + (size_t)node * STR;  // uniform ptr
    const unsigned loff = (unsigned)(ch * 64 + lane) * 4u;

    float2 acc = make_float2(0.f, 0.f);
    unsigned e = 0;
    for (; e + 8 <= deg; e += 8) {
        unsigned o0 = el[e + 0], o1 = el[e + 1], o2 = el[e + 2], o3 = el[e + 3];
        unsigned o4 = el[e + 4], o5 = el[e + 5], o6 = el[e + 6], o7 = el[e + 7];
        const unsigned v0 = *reinterpret_cast<const unsigned*>(W1b + (o0 + loff));
        const unsigned v1 = *reinterpret_cast<const unsigned*>(W1b + (o1 + loff));
        const unsigned v2 = *reinterpret_cast<const unsigned*>(W1b + (o2 + loff));
        const unsigned v3 = *reinterpret_cast<const unsigned*>(W1b + (o3 + loff));
        const unsigned v4 = *reinterpret_cast<const unsigned*>(W1b + (o4 + loff));
        const unsigned v5 = *reinterpret_cast<const unsigned*>(W1b + (o5 + loff));
        const unsigned v6 = *reinterpret_cast<const unsigned*>(W1b + (o6 + loff));
        const unsigned v7 = *reinterpret_cast<const unsigned*>(W1b + (o7 + loff));
        acc2p(acc, v0); acc2p(acc, v1); acc2p(acc, v2); acc2p(acc, v3);
        acc2p(acc, v4); acc2p(acc, v5); acc2p(acc, v6); acc2p(acc, v7);
    }
    for (; e < deg; ++e) {
        unsigned o = el[e];
        acc2p(acc, *reinterpret_cast<const unsigned*>(W1b + (o + loff)));
    }

    const float dr = rsqrtf((float)colfill[node]);
    __builtin_nontemporal_store(pack2(dr * acc.x, dr * acc.y),
                                &Mh[(size_t)node * (HH / 2) + ch * 64 + lane]);
}

// ---------------------------------------------------------------------------
// Scalar-pipe gather conv1 (same structure):
// hB[c, ch] = bf16( relu(dinv[c]*sum_{rn in cscA(c)} Mh[rn,ch] + b1) )
// (Mh pre-scaled by dinv[rn].)
// ---------------------------------------------------------------------------
__global__ __launch_bounds__(256) void k_conv1(const char* __restrict__ Mb,
                                               const float* __restrict__ b1,
                                               const unsigned* __restrict__ colfill,
                                               const unsigned* __restrict__ cscA,
                                               unsigned* __restrict__ hB) {
    const unsigned L = blockIdx.x;
    const int xcd   = L & 7;
    const unsigned k = L >> 3;
    const int phase = k >> 11;
    const int pix   = k & 2047;
    const int ch    = xcd + (phase << 3);
    int node = (pix << 2) | (threadIdx.x >> 6);
    node = __builtin_amdgcn_readfirstlane(node);
    const int lane = threadIdx.x & 63;

    unsigned deg = colfill[node];
    const float dc = rsqrtf((float)deg);
    if (deg > STR) deg = STR;
    const unsigned* __restrict__ el = cscA + (size_t)node * STR;  // uniform ptr
    const unsigned loff = (unsigned)(ch * 64 + lane) * 4u;

    float2 acc = make_float2(0.f, 0.f);
    unsigned e = 0;
    for (; e + 8 <= deg; e += 8) {
        unsigned o0 = el[e + 0], o1 = el[e + 1], o2 = el[e + 2], o3 = el[e + 3];
        unsigned o4 = el[e + 4], o5 = el[e + 5], o6 = el[e + 6], o7 = el[e + 7];
        const unsigned v0 = *reinterpret_cast<const unsigned*>(Mb + (o0 + loff));
        const unsigned v1 = *reinterpret_cast<const unsigned*>(Mb + (o1 + loff));
        const unsigned v2 = *reinterpret_cast<const unsigned*>(Mb + (o2 + loff));
        const unsigned v3 = *reinterpret_cast<const unsigned*>(Mb + (o3 + loff));
        const unsigned v4 = *reinterpret_cast<const unsigned*>(Mb + (o4 + loff));
        const unsigned v5 = *reinterpret_cast<const unsigned*>(Mb + (o5 + loff));
        const unsigned v6 = *reinterpret_cast<const unsigned*>(Mb + (o6 + loff));
        const unsigned v7 = *reinterpret_cast<const unsigned*>(Mb + (o7 + loff));
        acc2p(acc, v0); acc2p(acc, v1); acc2p(acc, v2); acc2p(acc, v3);
        acc2p(acc, v4); acc2p(acc, v5); acc2p(acc, v6); acc2p(acc, v7);
    }
    for (; e < deg; ++e) {
        unsigned o = el[e];
        acc2p(acc, *reinterpret_cast<const unsigned*>(Mb + (o + loff)));
    }

    const float2 bv = reinterpret_cast<const float2*>(b1)[ch * 64 + lane];
    const float h0 = fmaxf(fmaf(dc, acc.x, bv.x), 0.0f);
    const float h1 = fmaxf(fmaf(dc, acc.y, bv.y), 0.0f);
    __builtin_nontemporal_store(pack2(h0, h1),
                                &hB[(size_t)node * (HH / 2) + ch * 64 + lane]);
}

// ---------------------------------------------------------------------------
// Pool stage A: partial t per 32-row group, NO atomics. grid (2, 256).
// ---------------------------------------------------------------------------
__global__ __launch_bounds__(256) void k_poolA(const uint4* __restrict__ hB,
                                               const float* __restrict__ s,
                                               float* __restrict__ part) {
    const int j = blockIdx.x * 256 + threadIdx.x;      // uint4 col index
    const int c0 = blockIdx.y * (NN / PRG);            // 32 rows
    __shared__ float s_t[GG * (NN / PRG)];
    if (threadIdx.x < GG * (NN / PRG)) {
        const int g = threadIdx.x / (NN / PRG);
        const int cc = threadIdx.x % (NN / PRG);
        s_t[threadIdx.x] = s[(size_t)g * NN + c0 + cc];
    }
    __syncthreads();
    float tacc[GG][8];
    #pragma unroll
    for (int g = 0; g < GG; ++g)
        #pragma unroll
        for (int q = 0; q < 8; ++q) tacc[g][q] = 0.0f;
    for (int cc = 0; cc < NN / PRG; ++cc) {
        const uint4 v = hB[(size_t)(c0 + cc) * (HH / 8) + j];
        float hv[8];
        unpack8(v, hv);
        #pragma unroll
        for (int g = 0; g < GG; ++g) {
            const float sv = s_t[g * (NN / PRG) + cc];
            #pragma unroll
            for (int q = 0; q < 8; ++q) tacc[g][q] = fmaf(sv, hv[q], tacc[g][q]);
        }
    }
    float4* p4 = reinterpret_cast<float4*>(part);
    #pragma unroll
    for (int g = 0; g < GG; ++g) {
        const size_t base = ((size_t)(blockIdx.y * GG + g) * HH) / 4 + j * 2;
        p4[base]     = make_float4(tacc[g][0], tacc[g][1], tacc[g][2], tacc[g][3]);
        p4[base + 1] = make_float4(tacc[g][4], tacc[g][5], tacc[g][6], tacc[g][7]);
    }
}

// Pool stage B: t[g][j] = sum_rg part[rg][g][j]
__global__ __launch_bounds__(256) void k_poolB(const float* __restrict__ part,
                                               float* __restrict__ t) {
    const int idx = blockIdx.x * 256 + threadIdx.x;    // float4 index into t
    const int g = idx / (HH / 4);
    const int j4 = idx % (HH / 4);
    const float4* p4 = reinterpret_cast<const float4*>(part);
    float4 acc = make_float4(0.f, 0.f, 0.f, 0.f);
    for (int rg = 0; rg < PRG; ++rg) {
        const float4 v = p4[((size_t)(rg * GG + g) * HH) / 4 + j4];
        acc.x += v.x; acc.y += v.y; acc.z += v.z; acc.w += v.w;
    }
    reinterpret_cast<float4*>(t)[idx] = acc;
}

// ---------------------------------------------------------------------------
// Final stage A: part2[jg][g][n] = sum_{j in 64-jgroup} (t[g,j]/cnt[g])*W2[j,n]
// grid (NN/1024, FJG) = (8, 64) = 512 blocks.
// ---------------------------------------------------------------------------
__global__ __launch_bounds__(256) void k_final(const float* __restrict__ W2,
                                               const float* __restrict__ t,
                                               const unsigned* __restrict__ cnt,
                                               float* __restrict__ part2) {
    __shared__ float tld[GG * 64];
    const int tj = threadIdx.x;
    const int j0 = blockIdx.y * 64;
    const int nbase = blockIdx.x * 1024;
    for (int i = threadIdx.x; i < GG * 64; i += 256) {
        const int g = i >> 6;
        const int jj = i & 63;
        unsigned c = cnt[g];
        if (c < 1u) c = 1u;
        tld[i] = t[(size_t)g * HH + j0 + jj] * (1.0f / (float)c);
    }
    __syncthreads();
    float4 acc[GG];
    #pragma unroll
    for (int g = 0; g < GG; ++g) acc[g] = make_float4(0.f, 0.f, 0.f, 0.f);
    for (int jj = 0; jj < 64; ++jj) {
        const int jv = j0 + jj;
        float4 w = reinterpret_cast<const float4*>(W2 + (size_t)jv * NN + nbase)[tj];
        #pragma unroll
        for (int g = 0; g < GG; ++g) {
            const float tv = tld[g * 64 + jj];
            acc[g].x = fmaf(tv, w.x, acc[g].x);
            acc[g].y = fmaf(tv, w.y, acc[g].y);
            acc[g].z = fmaf(tv, w.z, acc[g].z);
            acc[g].w = fmaf(tv, w.w, acc[g].w);
        }
    }
    float4* p4 = reinterpret_cast<float4*>(part2);
    #pragma unroll
    for (int g = 0; g < GG; ++g)
        p4[((size_t)(blockIdx.y * GG + g) * NN + nbase) / 4 + tj] = acc[g];
}

// Final stage B: out[g][n] = b2[n] + sum_jg part2[jg][g][n]
__global__ __launch_bounds__(256) void k_fin2(const float* __restrict__ part2,
                                              const float* __restrict__ b2,
                                              float* __restrict__ out) {
    const int idx = blockIdx.x * 256 + threadIdx.x;    // float4 index into out
    const int g = idx / (NN / 4);
    const int n4 = idx % (NN / 4);
    const float4* p4 = reinterpret_cast<const float4*>(part2);
    float4 acc = reinterpret_cast<const float4*>(b2)[n4];
    for (int jg = 0; jg < FJG; ++jg) {
        const float4 v = p4[((size_t)(jg * GG + g) * NN) / 4 + n4];
        acc.x += v.x; acc.y += v.y; acc.z += v.z; acc.w += v.w;
    }
    reinterpret_cast<float4*>(out)[idx] = acc;
}

extern "C" void kernel_launch(void* const* d_in, const int* in_sizes, int n_in,
                              void* d_out, int out_size, void* d_ws, size_t ws_size,
                              hipStream_t stream) {
    const float* x  = (const float*)d_in[0];
    const float* W1 = (const float*)d_in[1];
    const float* b1 = (const float*)d_in[2];
    const float* W2 = (const float*)d_in[3];
    const float* b2 = (const float*)d_in[4];
    const int* batch = (const int*)d_in[5];
    float* out = (float*)d_out;

    char* ws = (char*)d_ws;
    size_t off = 0;
    auto alloc = [&](size_t bytes) -> char* {
        char* p = ws + off;
        off = (off + bytes + 255) & ~(size_t)255;
        return p;
    };
    uint4*    Mh      = (uint4*)   alloc((size_t)NN * HH * 2);   // bf16 M (dinv-scaled)
    uint4*    W1h     = (uint4*)   alloc((size_t)NN * HH * 2);   // bf16 W1; REUSED as hB
    uint4*    hB      = W1h;   // h overlays W1h (dead after k_spmm1; stream-serial)
    char*     zbegin  = ws + off;
    float*    t       = (float*)   alloc((size_t)GG * HH * 4);
    unsigned* colfill = (unsigned*)alloc((size_t)NN * 4);
    unsigned* cnt     = (unsigned*)alloc((size_t)GG * 4);
    char*     zend    = ws + off;
    float*    s       = (float*)   alloc((size_t)GG * NN * 4);
    unsigned* degX    = (unsigned*)alloc((size_t)NN * 4);
    unsigned* degA    = (unsigned*)alloc((size_t)NN * 4);
    unsigned* csrX    = (unsigned*)alloc((size_t)NN * STR * 4);  // 4 MB
    unsigned* csrA    = (unsigned*)alloc((size_t)NN * STR * 4);  // 4 MB
    unsigned* cscA    = (unsigned*)alloc((size_t)NN * STR * 4);  // 4 MB
    // part (poolA->poolB, 32 MiB) and part2 (final->fin2, 16 MiB) overlay the
    // Mh region: Mh is dead after k_conv1 completes (stream-serial), and
    // part/part2 occupy disjoint sub-ranges [0,32MiB) and [32,48MiB).
    float*    part    = (float*)Mh;
    float*    part2   = (float*)((char*)Mh + ((size_t)32 << 20));
    (void)ws_size; (void)in_sizes; (void)n_in; (void)out_size;

    hipMemsetAsync(zbegin, 0, (size_t)(zend - zbegin), stream);

    k_front<<<NN + (NN * HH / 8) / 256, 256, 0, stream>>>(x, W1, (uint4*)W1h, colfill,
                                                          degX, degA, csrX, csrA, cscA);
    k_s<<<NN / 256, 256, 0, stream>>>(degA, csrA, colfill, batch, s, cnt);
    k_spmm1<<<(NN / 4) * NCH, 256, 0, stream>>>((const char*)W1h, degX, csrX, colfill,
                                                (unsigned*)Mh);
    k_conv1<<<(NN / 4) * NCH, 256, 0, stream>>>((const char*)Mh, b1, colfill, cscA,
                                                (unsigned*)hB);
    k_poolA<<<dim3(HH / 2048, PRG), 256, 0, stream>>>(hB, s, part);
    k_poolB<<<(GG * HH / 4) / 256, 256, 0, stream>>>(part, t);
    k_final<<<dim3(NN / 1024, FJG), 256, 0, stream>>>(W2, t, cnt, part2);
    k_fin2<<<(GG * NN / 4) / 256, 256, 0, stream>>>(part2, b2, out);
}

// Round 16
// 580.261 us; speedup vs baseline: 1.1957x; 1.0303x over previous
//
#include <hip/hip_runtime.h>
#include <hip/hip_bf16.h>

#define NN 8192
#define HH 4096
#define GG 8
#define STR 128            // fixed stride for per-node edge lists (max deg ~57)
#define NCH 32             // H chunks (128 cols = 2 MB/chunk in bf16)
#define PRG 256            // pool row-groups (32 rows each) -> 512 blocks
#define FJG 64             // final j-groups (64 j each)     -> 512 blocks

typedef unsigned uint4n __attribute__((ext_vector_type(4)));  // native vec for NT stores

// ---------------------------------------------------------------------------
// bf16 helpers (packed 2x bf16 per u32; element 2q in low 16 bits)
// ---------------------------------------------------------------------------
__device__ inline unsigned bf16rne(float f) {
    unsigned u = __float_as_uint(f);
    unsigned r = 0x7fffu + ((u >> 16) & 1u);
    return (u + r) >> 16;
}
__device__ inline unsigned pack2(float lo, float hi) {
    return bf16rne(lo) | (bf16rne(hi) << 16);
}
__device__ inline void nt_store16(void* p, unsigned a, unsigned b, unsigned c, unsigned d) {
    uint4n v; v.x = a; v.y = b; v.z = c; v.w = d;
    __builtin_nontemporal_store(v, reinterpret_cast<uint4n*>(p));
}
// acc (2 elems) += unpacked u32 via packed add
__device__ inline void acc2p(float2& acc, unsigned u) {
    float2 t;
    t.x = __uint_as_float(u << 16);
    t.y = __uint_as_float(u & 0xffff0000u);
    asm("v_pk_add_f32 %0, %1, %0" : "+v"(acc) : "v"(t));
}
__device__ inline void unpack8(uint4 v, float* __restrict__ h) {
    const unsigned* pu = reinterpret_cast<const unsigned*>(&v);
    #pragma unroll
    for (int q = 0; q < 4; ++q) {
        const unsigned u = pu[q];
        h[2 * q]     = __uint_as_float(u << 16);
        h[2 * q + 1] = __uint_as_float(u & 0xffff0000u);
    }
}

// ---------------------------------------------------------------------------
// Fused front kernel. Blocks [0, NN): single-pass graph build (reads x once,
// with all-zero float4 fast path — x is 99.6% zeros). Blocks [NN, ...): W1
// fp32 -> bf16 convert (NT stores).
// csrX / cscA store PRE-SHIFTED byte offsets (idx << 13 = idx * HH * 2B);
// csrA stores plain indices (consumed by k_s).
// ---------------------------------------------------------------------------
__global__ __launch_bounds__(256) void k_front(const float* __restrict__ x,
                                               const float* __restrict__ W1,
                                               uint4* __restrict__ W1h,
                                               unsigned* __restrict__ colfill,
                                               unsigned* __restrict__ degX,
                                               unsigned* __restrict__ degA,
                                               unsigned* __restrict__ csrX,
                                               unsigned* __restrict__ csrA,
                                               unsigned* __restrict__ cscA) {
    __shared__ unsigned px, pa;
    const int bid = blockIdx.x;
    if (bid >= NN) {
        // ---- cvt part ----
        const size_t i = (size_t)(bid - NN) * 256 + threadIdx.x;
        const float4 a = reinterpret_cast<const float4*>(W1)[2 * i];
        const float4 b = reinterpret_cast<const float4*>(W1)[2 * i + 1];
        nt_store16(&W1h[i], pack2(a.x, a.y), pack2(a.z, a.w),
                            pack2(b.x, b.y), pack2(b.z, b.w));
        return;
    }
    // ---- build part: row bid ----
    const int r = bid;
    const int rq = r >> 2;                  // quad index containing the diagonal
    if (threadIdx.x == 0) { px = 0u; pa = 0u; }
    __syncthreads();
    const float4* xr = reinterpret_cast<const float4*>(x + (size_t)r * NN);
    #pragma unroll
    for (int i = 0; i < NN / (4 * 256); ++i) {
        const int c4 = i * 256 + threadIdx.x;
        float4 v = xr[c4];
        const bool any = (v.x != 0.0f) || (v.y != 0.0f) || (v.z != 0.0f) || (v.w != 0.0f);
        if (!any && (c4 != rq)) continue;   // fast path: ~99% of quads
        const float* vp = reinterpret_cast<const float*>(&v);
        #pragma unroll
        for (int k = 0; k < 4; ++k) {
            const int c = c4 * 4 + k;
            const bool nzx = (vp[k] != 0.0f);
            const bool nzA = nzx || (c == r);
            if (nzx) {
                unsigned p = atomicAdd(&px, 1u);
                if (p < STR) csrX[(size_t)r * STR + p] = (unsigned)c << 13;
            }
            if (nzA) {
                unsigned p = atomicAdd(&pa, 1u);
                if (p < STR) csrA[(size_t)r * STR + p] = (unsigned)c;
                unsigned q = atomicAdd(&colfill[c], 1u);
                if (q < STR) cscA[(size_t)c * STR + q] = (unsigned)r << 13;
            }
        }
    }
    __syncthreads();
    if (threadIdx.x == 0) { degX[r] = px; degA[r] = pa; }
}

// ---------------------------------------------------------------------------
// Pooled adjacency, wave-per-row: lanes cover edges in parallel, per-group
// sums via 6-step shfl_xor butterfly. grid NN/4 blocks x 4 waves.
// s[g][r] = dinv[r] * sum_{c in rowA(r), batch[c]==g} dinv[c]
// ---------------------------------------------------------------------------
__global__ __launch_bounds__(256) void k_s(const unsigned* __restrict__ degA,
                                           const unsigned* __restrict__ csrA,
                                           const unsigned* __restrict__ colfill,
                                           const int* __restrict__ batch,
                                           float* __restrict__ s,
                                           unsigned* __restrict__ cnt) {
    const int wid  = threadIdx.x >> 6;
    const int lane = threadIdx.x & 63;
    const int r = blockIdx.x * 4 + wid;
    unsigned deg = degA[r];
    if (deg > STR) deg = STR;
    float bins[GG];
    #pragma unroll
    for (int g = 0; g < GG; ++g) bins[g] = 0.0f;
    for (unsigned e = lane; e < deg; e += 64) {
        const unsigned c = csrA[(size_t)r * STR + e];
        const float d = rsqrtf((float)colfill[c]);
        const int gb = batch[c];
        #pragma unroll
        for (int g = 0; g < GG; ++g) bins[g] += (gb == g) ? d : 0.0f;
    }
    #pragma unroll
    for (int g = 0; g < GG; ++g) {
        #pragma unroll
        for (int off = 1; off < 64; off <<= 1)
            bins[g] += __shfl_xor(bins[g], off);
    }
    if (lane == 0) {
        atomicAdd(&cnt[batch[r]], 1u);
        const float dr = rsqrtf((float)colfill[r]);
        #pragma unroll
        for (int g = 0; g < GG; ++g) s[(size_t)g * NN + r] = dr * bins[g];
    }
}

// ---------------------------------------------------------------------------
// Scalar-pipe gather SpMM1 (r12 structure — proven floor). 1 wave = 1
// (node, 128-col chunk); 64 lanes x 1 u32 (2 bf16). Edge list wave-uniform
// (readfirstlane -> s_load offsets). XCD-pinned chunks; NT result store.
// Mh[r, ch] = bf16( dinv[r] * sum_{c in csrX(r)} W1h[c, ch] )
// ---------------------------------------------------------------------------
__global__ __launch_bounds__(256) void k_spmm1(const char* __restrict__ W1b,
                                               const unsigned* __restrict__ degX,
                                               const unsigned* __restrict__ csrX,
                                               const unsigned* __restrict__ colfill,
                                               unsigned* __restrict__ Mh) {
    const unsigned L = blockIdx.x;
    const int xcd   = L & 7;
    const unsigned k = L >> 3;
    const int phase = k >> 11;            // 2048 node-quads per phase
    const int pix   = k & 2047;
    const int ch    = xcd + (phase << 3); // this XCD's chunk set {x, x+8, x+16, x+24}
    int node = (pix << 2) | (threadIdx.x >> 6);
    node = __builtin_amdgcn_readfirstlane(node);
    const int lane = threadIdx.x & 63;

    unsigned deg = degX[node];
    if (deg > STR) deg = STR;
    const unsigned* __restrict__ el = csrX + (size_t)node * STR;  // uniform ptr
    const unsigned loff = (unsigned)(ch * 64 + lane) * 4u;

    float2 acc = make_float2(0.f, 0.f);
    unsigned e = 0;
    for (; e + 8 <= deg; e += 8) {
        unsigned o0 = el[e + 0], o1 = el[e + 1], o2 = el[e + 2], o3 = el[e + 3];
        unsigned o4 = el[e + 4], o5 = el[e + 5], o6 = el[e + 6], o7 = el[e + 7];
        const unsigned v0 = *reinterpret_cast<const unsigned*>(W1b + (o0 + loff));
        const unsigned v1 = *reinterpret_cast<const unsigned*>(W1b + (o1 + loff));
        const unsigned v2 = *reinterpret_cast<const unsigned*>(W1b + (o2 + loff));
        const unsigned v3 = *reinterpret_cast<const unsigned*>(W1b + (o3 + loff));
        const unsigned v4 = *reinterpret_cast<const unsigned*>(W1b + (o4 + loff));
        const unsigned v5 = *reinterpret_cast<const unsigned*>(W1b + (o5 + loff));
        const unsigned v6 = *reinterpret_cast<const unsigned*>(W1b + (o6 + loff));
        const unsigned v7 = *reinterpret_cast<const unsigned*>(W1b + (o7 + loff));
        acc2p(acc, v0); acc2p(acc, v1); acc2p(acc, v2); acc2p(acc, v3);
        acc2p(acc, v4); acc2p(acc, v5); acc2p(acc, v6); acc2p(acc, v7);
    }
    for (; e < deg; ++e) {
        unsigned o = el[e];
        acc2p(acc, *reinterpret_cast<const unsigned*>(W1b + (o + loff)));
    }

    const float dr = rsqrtf((float)colfill[node]);
    __builtin_nontemporal_store(pack2(dr * acc.x, dr * acc.y),
                                &Mh[(size_t)node * (HH / 2) + ch * 64 + lane]);
}

// ---------------------------------------------------------------------------
// Scalar-pipe gather conv1 (same structure):
// hB[c, ch] = bf16( relu(dinv[c]*sum_{rn in cscA(c)} Mh[rn,ch] + b1) )
// (Mh pre-scaled by dinv[rn].)
// ---------------------------------------------------------------------------
__global__ __launch_bounds__(256) void k_conv1(const char* __restrict__ Mb,
                                               const float* __restrict__ b1,
                                               const unsigned* __restrict__ colfill,
                                               const unsigned* __restrict__ cscA,
                                               unsigned* __restrict__ hB) {
    const unsigned L = blockIdx.x;
    const int xcd   = L & 7;
    const unsigned k = L >> 3;
    const int phase = k >> 11;
    const int pix   = k & 2047;
    const int ch    = xcd + (phase << 3);
    int node = (pix << 2) | (threadIdx.x >> 6);
    node = __builtin_amdgcn_readfirstlane(node);
    const int lane = threadIdx.x & 63;

    unsigned deg = colfill[node];
    const float dc = rsqrtf((float)deg);
    if (deg > STR) deg = STR;
    const unsigned* __restrict__ el = cscA + (size_t)node * STR;  // uniform ptr
    const unsigned loff = (unsigned)(ch * 64 + lane) * 4u;

    float2 acc = make_float2(0.f, 0.f);
    unsigned e = 0;
    for (; e + 8 <= deg; e += 8) {
        unsigned o0 = el[e + 0], o1 = el[e + 1], o2 = el[e + 2], o3 = el[e + 3];
        unsigned o4 = el[e + 4], o5 = el[e + 5], o6 = el[e + 6], o7 = el[e + 7];
        const unsigned v0 = *reinterpret_cast<const unsigned*>(Mb + (o0 + loff));
        const unsigned v1 = *reinterpret_cast<const unsigned*>(Mb + (o1 + loff));
        const unsigned v2 = *reinterpret_cast<const unsigned*>(Mb + (o2 + loff));
        const unsigned v3 = *reinterpret_cast<const unsigned*>(Mb + (o3 + loff));
        const unsigned v4 = *reinterpret_cast<const unsigned*>(Mb + (o4 + loff));
        const unsigned v5 = *reinterpret_cast<const unsigned*>(Mb + (o5 + loff));
        const unsigned v6 = *reinterpret_cast<const unsigned*>(Mb + (o6 + loff));
        const unsigned v7 = *reinterpret_cast<const unsigned*>(Mb + (o7 + loff));
        acc2p(acc, v0); acc2p(acc, v1); acc2p(acc, v2); acc2p(acc, v3);
        acc2p(acc, v4); acc2p(acc, v5); acc2p(acc, v6); acc2p(acc, v7);
    }
    for (; e < deg; ++e) {
        unsigned o = el[e];
        acc2p(acc, *reinterpret_cast<const unsigned*>(Mb + (o + loff)));
    }

    const float2 bv = reinterpret_cast<const float2*>(b1)[ch * 64 + lane];
    const float h0 = fmaxf(fmaf(dc, acc.x, bv.x), 0.0f);
    const float h1 = fmaxf(fmaf(dc, acc.y, bv.y), 0.0f);
    __builtin_nontemporal_store(pack2(h0, h1),
                                &hB[(size_t)node * (HH / 2) + ch * 64 + lane]);
}

// ---------------------------------------------------------------------------
// Pool stage A: partial t per 32-row group, NO atomics. grid (2, 256).
// ---------------------------------------------------------------------------
__global__ __launch_bounds__(256) void k_poolA(const uint4* __restrict__ hB,
                                               const float* __restrict__ s,
                                               float* __restrict__ part) {
    const int j = blockIdx.x * 256 + threadIdx.x;      // uint4 col index
    const int c0 = blockIdx.y * (NN / PRG);            // 32 rows
    __shared__ float s_t[GG * (NN / PRG)];
    if (threadIdx.x < GG * (NN / PRG)) {
        const int g = threadIdx.x / (NN / PRG);
        const int cc = threadIdx.x % (NN / PRG);
        s_t[threadIdx.x] = s[(size_t)g * NN + c0 + cc];
    }
    __syncthreads();
    float tacc[GG][8];
    #pragma unroll
    for (int g = 0; g < GG; ++g)
        #pragma unroll
        for (int q = 0; q < 8; ++q) tacc[g][q] = 0.0f;
    for (int cc = 0; cc < NN / PRG; ++cc) {
        const uint4 v = hB[(size_t)(c0 + cc) * (HH / 8) + j];
        float hv[8];
        unpack8(v, hv);
        #pragma unroll
        for (int g = 0; g < GG; ++g) {
            const float sv = s_t[g * (NN / PRG) + cc];
            #pragma unroll
            for (int q = 0; q < 8; ++q) tacc[g][q] = fmaf(sv, hv[q], tacc[g][q]);
        }
    }
    float4* p4 = reinterpret_cast<float4*>(part);
    #pragma unroll
    for (int g = 0; g < GG; ++g) {
        const size_t base = ((size_t)(blockIdx.y * GG + g) * HH) / 4 + j * 2;
        p4[base]     = make_float4(tacc[g][0], tacc[g][1], tacc[g][2], tacc[g][3]);
        p4[base + 1] = make_float4(tacc[g][4], tacc[g][5], tacc[g][6], tacc[g][7]);
    }
}

// Pool stage B1: parts[q][g][j] = sum_{rg in [32q,32q+32)} part[rg][g][j]
// grid (32, 8) = 256 blocks.
__global__ __launch_bounds__(256) void k_poolB1(const float* __restrict__ part,
                                                float* __restrict__ parts) {
    const int idx = blockIdx.x * 256 + threadIdx.x;    // (g, j4): 8192 float4
    const int q = blockIdx.y;
    const int g = idx / (HH / 4);
    const int j4 = idx % (HH / 4);
    const float4* p4 = reinterpret_cast<const float4*>(part);
    float4 acc = make_float4(0.f, 0.f, 0.f, 0.f);
    for (int rg = q * 32; rg < q * 32 + 32; ++rg) {
        const float4 v = p4[((size_t)(rg * GG + g) * HH) / 4 + j4];
        acc.x += v.x; acc.y += v.y; acc.z += v.z; acc.w += v.w;
    }
    reinterpret_cast<float4*>(parts)[(size_t)q * (GG * HH / 4) + idx] = acc;
}

// Pool stage B2: t[g][j] = sum_q parts[q][g][j].  32 blocks.
__global__ __launch_bounds__(256) void k_poolB2(const float* __restrict__ parts,
                                                float* __restrict__ t) {
    const int idx = blockIdx.x * 256 + threadIdx.x;
    const float4* p4 = reinterpret_cast<const float4*>(parts);
    float4 acc = make_float4(0.f, 0.f, 0.f, 0.f);
    #pragma unroll
    for (int q = 0; q < 8; ++q) {
        const float4 v = p4[(size_t)q * (GG * HH / 4) + idx];
        acc.x += v.x; acc.y += v.y; acc.z += v.z; acc.w += v.w;
    }
    reinterpret_cast<float4*>(t)[idx] = acc;
}

// ---------------------------------------------------------------------------
// Final stage A: part2[jg][g][n] = sum_{j in 64-jgroup} (t[g,j]/cnt[g])*W2[j,n]
// grid (NN/1024, FJG) = (8, 64) = 512 blocks.
// ---------------------------------------------------------------------------
__global__ __launch_bounds__(256) void k_final(const float* __restrict__ W2,
                                               const float* __restrict__ t,
                                               const unsigned* __restrict__ cnt,
                                               float* __restrict__ part2) {
    __shared__ float tld[GG * 64];
    const int tj = threadIdx.x;
    const int j0 = blockIdx.y * 64;
    const int nbase = blockIdx.x * 1024;
    for (int i = threadIdx.x; i < GG * 64; i += 256) {
        const int g = i >> 6;
        const int jj = i & 63;
        unsigned c = cnt[g];
        if (c < 1u) c = 1u;
        tld[i] = t[(size_t)g * HH + j0 + jj] * (1.0f / (float)c);
    }
    __syncthreads();
    float4 acc[GG];
    #pragma unroll
    for (int g = 0; g < GG; ++g) acc[g] = make_float4(0.f, 0.f, 0.f, 0.f);
    for (int jj = 0; jj < 64; ++jj) {
        const int jv = j0 + jj;
        float4 w = reinterpret_cast<const float4*>(W2 + (size_t)jv * NN + nbase)[tj];
        #pragma unroll
        for (int g = 0; g < GG; ++g) {
            const float tv = tld[g * 64 + jj];
            acc[g].x = fmaf(tv, w.x, acc[g].x);
            acc[g].y = fmaf(tv, w.y, acc[g].y);
            acc[g].z = fmaf(tv, w.z, acc[g].z);
            acc[g].w = fmaf(tv, w.w, acc[g].w);
        }
    }
    float4* p4 = reinterpret_cast<float4*>(part2);
    #pragma unroll
    for (int g = 0; g < GG; ++g)
        p4[((size_t)(blockIdx.y * GG + g) * NN + nbase) / 4 + tj] = acc[g];
}

// Final stage B1: part3[q][g][n] = sum_{jg in [8q,8q+8)} part2[jg][g][n]
// grid (64, 8) = 512 blocks.
__global__ __launch_bounds__(256) void k_fin2a(const float* __restrict__ part2,
                                               float* __restrict__ part3) {
    const int idx = blockIdx.x * 256 + threadIdx.x;    // (g, n4): 16384 float4
    const int q = blockIdx.y;
    const int g = idx / (NN / 4);
    const int n4 = idx % (NN / 4);
    const float4* p4 = reinterpret_cast<const float4*>(part2);
    float4 acc = make_float4(0.f, 0.f, 0.f, 0.f);
    for (int jg = q * 8; jg < q * 8 + 8; ++jg) {
        const float4 v = p4[((size_t)(jg * GG + g) * NN) / 4 + n4];
        acc.x += v.x; acc.y += v.y; acc.z += v.z; acc.w += v.w;
    }
    reinterpret_cast<float4*>(part3)[(size_t)q * (GG * NN / 4) + idx] = acc;
}

// Final stage B2: out[g][n] = b2[n] + sum_q part3[q][g][n].  64 blocks.
__global__ __launch_bounds__(256) void k_fin2b(const float* __restrict__ part3,
                                               const float* __restrict__ b2,
                                               float* __restrict__ out) {
    const int idx = blockIdx.x * 256 + threadIdx.x;
    const int n4 = idx % (NN / 4);
    const float4* p4 = reinterpret_cast<const float4*>(part3);
    float4 acc = reinterpret_cast<const float4*>(b2)[n4];
    #pragma unroll
    for (int q = 0; q < 8; ++q) {
        const float4 v = p4[(size_t)q * (GG * NN / 4) + idx];
        acc.x += v.x; acc.y += v.y; acc.z += v.z; acc.w += v.w;
    }
    reinterpret_cast<float4*>(out)[idx] = acc;
}

extern "C" void kernel_launch(void* const* d_in, const int* in_sizes, int n_in,
                              void* d_out, int out_size, void* d_ws, size_t ws_size,
                              hipStream_t stream) {
    const float* x  = (const float*)d_in[0];
    const float* W1 = (const float*)d_in[1];
    const float* b1 = (const float*)d_in[2];
    const float* W2 = (const float*)d_in[3];
    const float* b2 = (const float*)d_in[4];
    const int* batch = (const int*)d_in[5];
    float* out = (float*)d_out;

    char* ws = (char*)d_ws;
    size_t off = 0;
    auto alloc = [&](size_t bytes) -> char* {
        char* p = ws + off;
        off = (off + bytes + 255) & ~(size_t)255;
        return p;
    };
    uint4*    Mh      = (uint4*)   alloc((size_t)NN * HH * 2);   // bf16 M (dinv-scaled)
    uint4*    W1h     = (uint4*)   alloc((size_t)NN * HH * 2);   // bf16 W1; REUSED as hB
    uint4*    hB      = W1h;   // h overlays W1h (dead after k_spmm1; stream-serial)
    char*     zbegin  = ws + off;
    float*    t       = (float*)   alloc((size_t)GG * HH * 4);
    unsigned* colfill = (unsigned*)alloc((size_t)NN * 4);
    unsigned* cnt     = (unsigned*)alloc((size_t)GG * 4);
    char*     zend    = ws + off;
    float*    s       = (float*)   alloc((size_t)GG * NN * 4);
    unsigned* degX    = (unsigned*)alloc((size_t)NN * 4);
    unsigned* degA    = (unsigned*)alloc((size_t)NN * 4);
    unsigned* csrX    = (unsigned*)alloc((size_t)NN * STR * 4);  // 4 MB
    unsigned* csrA    = (unsigned*)alloc((size_t)NN * STR * 4);  // 4 MB
    unsigned* cscA    = (unsigned*)alloc((size_t)NN * STR * 4);  // 4 MB
    // Tail intermediates overlay the Mh region (Mh dead after k_conv1):
    //   part  [PRG][GG][HH]   32 MiB  @ [0, 32M)
    //   part2 [FJG][GG][NN]   16 MiB  @ [32M, 48M)
    //   part3 [8][GG][NN]      2 MiB  @ [48M, 50M)
    //   parts [8][GG][HH]      1 MiB  @ [50M, 51M)
    float*    part    = (float*)Mh;
    float*    part2   = (float*)((char*)Mh + ((size_t)32 << 20));
    float*    part3   = (float*)((char*)Mh + ((size_t)48 << 20));
    float*    parts   = (float*)((char*)Mh + ((size_t)50 << 20));
    (void)ws_size; (void)in_sizes; (void)n_in; (void)out_size;

    hipMemsetAsync(zbegin, 0, (size_t)(zend - zbegin), stream);

    k_front<<<NN + (NN * HH / 8) / 256, 256, 0, stream>>>(x, W1, (uint4*)W1h, colfill,
                                                          degX, degA, csrX, csrA, cscA);
    k_s<<<NN / 4, 256, 0, stream>>>(degA, csrA, colfill, batch, s, cnt);
    k_spmm1<<<(NN / 4) * NCH, 256, 0, stream>>>((const char*)W1h, degX, csrX, colfill,
                                                (unsigned*)Mh);
    k_conv1<<<(NN / 4) * NCH, 256, 0, stream>>>((const char*)Mh, b1, colfill, cscA,
                                                (unsigned*)hB);
    k_poolA<<<dim3(HH / 2048, PRG), 256, 0, stream>>>(hB, s, part);
    k_poolB1<<<dim3(32, 8), 256, 0, stream>>>(part, parts);
    k_poolB2<<<32, 256, 0, stream>>>(parts, t);
    k_final<<<dim3(NN / 1024, FJG), 256, 0, stream>>>(W2, t, cnt, part2);
    k_fin2a<<<dim3(64, 8), 256, 0, stream>>>(part2, part3);
    k_fin2b<<<64, 256, 0, stream>>>(part3, b2, out);
}

// Round 17
// 558.417 us; speedup vs baseline: 1.2424x; 1.0391x over previous
//
#include <hip/hip_runtime.h>
#include <hip/hip_bf16.h>

#define NN 8192
#define HH 4096
#define GG 8
#define STR 128            // fixed stride for per-node edge lists (max deg ~57)
#define NCH 16             // H chunks (256 cols = 4 MB/chunk in bf16) — 512B/edge test
#define PRG 256            // pool row-groups (32 rows each) -> 512 blocks
#define FJG 64             // final j-groups (64 j each)     -> 512 blocks

typedef unsigned uint4n __attribute__((ext_vector_type(4)));  // native vec for NT stores
typedef unsigned uint2n __attribute__((ext_vector_type(2)));

// ---------------------------------------------------------------------------
// bf16 helpers (packed 2x bf16 per u32; element 2q in low 16 bits)
// ---------------------------------------------------------------------------
__device__ inline unsigned bf16rne(float f) {
    unsigned u = __float_as_uint(f);
    unsigned r = 0x7fffu + ((u >> 16) & 1u);
    return (u + r) >> 16;
}
__device__ inline unsigned pack2(float lo, float hi) {
    return bf16rne(lo) | (bf16rne(hi) << 16);
}
__device__ inline void nt_store16(void* p, unsigned a, unsigned b, unsigned c, unsigned d) {
    uint4n v; v.x = a; v.y = b; v.z = c; v.w = d;
    __builtin_nontemporal_store(v, reinterpret_cast<uint4n*>(p));
}
__device__ inline void nt_store8(void* p, unsigned a, unsigned b) {
    uint2n v; v.x = a; v.y = b;
    __builtin_nontemporal_store(v, reinterpret_cast<uint2n*>(p));
}
// acc (2 elems) += unpacked u32 via packed add
__device__ inline void acc2p(float2& acc, unsigned u) {
    float2 t;
    t.x = __uint_as_float(u << 16);
    t.y = __uint_as_float(u & 0xffff0000u);
    asm("v_pk_add_f32 %0, %1, %0" : "+v"(acc) : "v"(t));
}
__device__ inline void unpack8(uint4 v, float* __restrict__ h) {
    const unsigned* pu = reinterpret_cast<const unsigned*>(&v);
    #pragma unroll
    for (int q = 0; q < 4; ++q) {
        const unsigned u = pu[q];
        h[2 * q]     = __uint_as_float(u << 16);
        h[2 * q + 1] = __uint_as_float(u & 0xffff0000u);
    }
}

// ---------------------------------------------------------------------------
// Fused front kernel. Blocks [0, NN): single-pass graph build (reads x once,
// with all-zero float4 fast path — x is 99.6% zeros). Blocks [NN, ...): W1
// fp32 -> bf16 convert (NT stores).
// csrX / cscA store PRE-SHIFTED byte offsets (idx << 13 = idx * HH * 2B);
// csrA stores plain indices (consumed by k_s).
// ---------------------------------------------------------------------------
__global__ __launch_bounds__(256) void k_front(const float* __restrict__ x,
                                               const float* __restrict__ W1,
                                               uint4* __restrict__ W1h,
                                               unsigned* __restrict__ colfill,
                                               unsigned* __restrict__ degX,
                                               unsigned* __restrict__ degA,
                                               unsigned* __restrict__ csrX,
                                               unsigned* __restrict__ csrA,
                                               unsigned* __restrict__ cscA) {
    __shared__ unsigned px, pa;
    const int bid = blockIdx.x;
    if (bid >= NN) {
        // ---- cvt part ----
        const size_t i = (size_t)(bid - NN) * 256 + threadIdx.x;
        const float4 a = reinterpret_cast<const float4*>(W1)[2 * i];
        const float4 b = reinterpret_cast<const float4*>(W1)[2 * i + 1];
        nt_store16(&W1h[i], pack2(a.x, a.y), pack2(a.z, a.w),
                            pack2(b.x, b.y), pack2(b.z, b.w));
        return;
    }
    // ---- build part: row bid ----
    const int r = bid;
    const int rq = r >> 2;                  // quad index containing the diagonal
    if (threadIdx.x == 0) { px = 0u; pa = 0u; }
    __syncthreads();
    const float4* xr = reinterpret_cast<const float4*>(x + (size_t)r * NN);
    #pragma unroll
    for (int i = 0; i < NN / (4 * 256); ++i) {
        const int c4 = i * 256 + threadIdx.x;
        float4 v = xr[c4];
        const bool any = (v.x != 0.0f) || (v.y != 0.0f) || (v.z != 0.0f) || (v.w != 0.0f);
        if (!any && (c4 != rq)) continue;   // fast path: ~99% of quads
        const float* vp = reinterpret_cast<const float*>(&v);
        #pragma unroll
        for (int k = 0; k < 4; ++k) {
            const int c = c4 * 4 + k;
            const bool nzx = (vp[k] != 0.0f);
            const bool nzA = nzx || (c == r);
            if (nzx) {
                unsigned p = atomicAdd(&px, 1u);
                if (p < STR) csrX[(size_t)r * STR + p] = (unsigned)c << 13;
            }
            if (nzA) {
                unsigned p = atomicAdd(&pa, 1u);
                if (p < STR) csrA[(size_t)r * STR + p] = (unsigned)c;
                unsigned q = atomicAdd(&colfill[c], 1u);
                if (q < STR) cscA[(size_t)c * STR + q] = (unsigned)r << 13;
            }
        }
    }
    __syncthreads();
    if (threadIdx.x == 0) { degX[r] = px; degA[r] = pa; }
}

// ---------------------------------------------------------------------------
// Pooled adjacency, wave-per-row: lanes cover edges in parallel, per-group
// sums via 6-step shfl_xor butterfly. grid NN/4 blocks x 4 waves.
// s[g][r] = dinv[r] * sum_{c in rowA(r), batch[c]==g} dinv[c]
// ---------------------------------------------------------------------------
__global__ __launch_bounds__(256) void k_s(const unsigned* __restrict__ degA,
                                           const unsigned* __restrict__ csrA,
                                           const unsigned* __restrict__ colfill,
                                           const int* __restrict__ batch,
                                           float* __restrict__ s,
                                           unsigned* __restrict__ cnt) {
    const int wid  = threadIdx.x >> 6;
    const int lane = threadIdx.x & 63;
    const int r = blockIdx.x * 4 + wid;
    unsigned deg = degA[r];
    if (deg > STR) deg = STR;
    float bins[GG];
    #pragma unroll
    for (int g = 0; g < GG; ++g) bins[g] = 0.0f;
    for (unsigned e = lane; e < deg; e += 64) {
        const unsigned c = csrA[(size_t)r * STR + e];
        const float d = rsqrtf((float)colfill[c]);
        const int gb = batch[c];
        #pragma unroll
        for (int g = 0; g < GG; ++g) bins[g] += (gb == g) ? d : 0.0f;
    }
    #pragma unroll
    for (int g = 0; g < GG; ++g) {
        #pragma unroll
        for (int off = 1; off < 64; off <<= 1)
            bins[g] += __shfl_xor(bins[g], off);
    }
    if (lane == 0) {
        atomicAdd(&cnt[batch[r]], 1u);
        const float dr = rsqrtf((float)colfill[r]);
        #pragma unroll
        for (int g = 0; g < GG; ++g) s[(size_t)g * NN + r] = dr * bins[g];
    }
}

// ---------------------------------------------------------------------------
// Scalar-pipe gather SpMM1, 512B-segment variant. 1 wave = 1 (node, 256-col
// chunk); 64 lanes x uint2 (4 bf16) = 512B contiguous per edge. Edge list
// wave-uniform (readfirstlane -> s_load offsets). XCD-pinned chunks (2
// phases: {xcd, xcd+8}); NT result store.
// Mh[r, ch] = bf16( dinv[r] * sum_{c in csrX(r)} W1h[c, ch] )
// ---------------------------------------------------------------------------
__global__ __launch_bounds__(256) void k_spmm1(const char* __restrict__ W1b,
                                               const unsigned* __restrict__ degX,
                                               const unsigned* __restrict__ csrX,
                                               const unsigned* __restrict__ colfill,
                                               unsigned* __restrict__ Mh) {
    const unsigned L = blockIdx.x;
    const int xcd   = L & 7;
    const unsigned k = L >> 3;
    const int phase = k >> 11;            // 2048 node-quads per phase; 2 phases
    const int pix   = k & 2047;
    const int ch    = xcd + (phase << 3); // this XCD's chunk set {x, x+8}
    int node = (pix << 2) | (threadIdx.x >> 6);
    node = __builtin_amdgcn_readfirstlane(node);
    const int lane = threadIdx.x & 63;

    unsigned deg = degX[node];
    if (deg > STR) deg = STR;
    const unsigned* __restrict__ el = csrX + (size_t)node * STR;  // uniform ptr
    const unsigned loff = (unsigned)(ch * 512) + (unsigned)lane * 8u;

    float2 accA = make_float2(0.f, 0.f);
    float2 accB = make_float2(0.f, 0.f);
    unsigned e = 0;
    for (; e + 8 <= deg; e += 8) {
        unsigned o0 = el[e + 0], o1 = el[e + 1], o2 = el[e + 2], o3 = el[e + 3];
        unsigned o4 = el[e + 4], o5 = el[e + 5], o6 = el[e + 6], o7 = el[e + 7];
        const uint2 v0 = *reinterpret_cast<const uint2*>(W1b + (o0 + loff));
        const uint2 v1 = *reinterpret_cast<const uint2*>(W1b + (o1 + loff));
        const uint2 v2 = *reinterpret_cast<const uint2*>(W1b + (o2 + loff));
        const uint2 v3 = *reinterpret_cast<const uint2*>(W1b + (o3 + loff));
        const uint2 v4 = *reinterpret_cast<const uint2*>(W1b + (o4 + loff));
        const uint2 v5 = *reinterpret_cast<const uint2*>(W1b + (o5 + loff));
        const uint2 v6 = *reinterpret_cast<const uint2*>(W1b + (o6 + loff));
        const uint2 v7 = *reinterpret_cast<const uint2*>(W1b + (o7 + loff));
        acc2p(accA, v0.x); acc2p(accB, v0.y);
        acc2p(accA, v1.x); acc2p(accB, v1.y);
        acc2p(accA, v2.x); acc2p(accB, v2.y);
        acc2p(accA, v3.x); acc2p(accB, v3.y);
        acc2p(accA, v4.x); acc2p(accB, v4.y);
        acc2p(accA, v5.x); acc2p(accB, v5.y);
        acc2p(accA, v6.x); acc2p(accB, v6.y);
        acc2p(accA, v7.x); acc2p(accB, v7.y);
    }
    for (; e < deg; ++e) {
        unsigned o = el[e];
        const uint2 v = *reinterpret_cast<const uint2*>(W1b + (o + loff));
        acc2p(accA, v.x); acc2p(accB, v.y);
    }

    const float dr = rsqrtf((float)colfill[node]);
    nt_store8(&Mh[(size_t)node * (HH / 2) + ch * 128 + lane * 2],
              pack2(dr * accA.x, dr * accA.y),
              pack2(dr * accB.x, dr * accB.y));
}

// ---------------------------------------------------------------------------
// Scalar-pipe gather conv1 (same 512B structure):
// hB[c, ch] = bf16( relu(dinv[c]*sum_{rn in cscA(c)} Mh[rn,ch] + b1) )
// (Mh pre-scaled by dinv[rn].)
// ---------------------------------------------------------------------------
__global__ __launch_bounds__(256) void k_conv1(const char* __restrict__ Mb,
                                               const float* __restrict__ b1,
                                               const unsigned* __restrict__ colfill,
                                               const unsigned* __restrict__ cscA,
                                               unsigned* __restrict__ hB) {
    const unsigned L = blockIdx.x;
    const int xcd   = L & 7;
    const unsigned k = L >> 3;
    const int phase = k >> 11;
    const int pix   = k & 2047;
    const int ch    = xcd + (phase << 3);
    int node = (pix << 2) | (threadIdx.x >> 6);
    node = __builtin_amdgcn_readfirstlane(node);
    const int lane = threadIdx.x & 63;

    unsigned deg = colfill[node];
    const float dc = rsqrtf((float)deg);
    if (deg > STR) deg = STR;
    const unsigned* __restrict__ el = cscA + (size_t)node * STR;  // uniform ptr
    const unsigned loff = (unsigned)(ch * 512) + (unsigned)lane * 8u;

    float2 accA = make_float2(0.f, 0.f);
    float2 accB = make_float2(0.f, 0.f);
    unsigned e = 0;
    for (; e + 8 <= deg; e += 8) {
        unsigned o0 = el[e + 0], o1 = el[e + 1], o2 = el[e + 2], o3 = el[e + 3];
        unsigned o4 = el[e + 4], o5 = el[e + 5], o6 = el[e + 6], o7 = el[e + 7];
        const uint2 v0 = *reinterpret_cast<const uint2*>(Mb + (o0 + loff));
        const uint2 v1 = *reinterpret_cast<const uint2*>(Mb + (o1 + loff));
        const uint2 v2 = *reinterpret_cast<const uint2*>(Mb + (o2 + loff));
        const uint2 v3 = *reinterpret_cast<const uint2*>(Mb + (o3 + loff));
        const uint2 v4 = *reinterpret_cast<const uint2*>(Mb + (o4 + loff));
        const uint2 v5 = *reinterpret_cast<const uint2*>(Mb + (o5 + loff));
        const uint2 v6 = *reinterpret_cast<const uint2*>(Mb + (o6 + loff));
        const uint2 v7 = *reinterpret_cast<const uint2*>(Mb + (o7 + loff));
        acc2p(accA, v0.x); acc2p(accB, v0.y);
        acc2p(accA, v1.x); acc2p(accB, v1.y);
        acc2p(accA, v2.x); acc2p(accB, v2.y);
        acc2p(accA, v3.x); acc2p(accB, v3.y);
        acc2p(accA, v4.x); acc2p(accB, v4.y);
        acc2p(accA, v5.x); acc2p(accB, v5.y);
        acc2p(accA, v6.x); acc2p(accB, v6.y);
        acc2p(accA, v7.x); acc2p(accB, v7.y);
    }
    for (; e < deg; ++e) {
        unsigned o = el[e];
        const uint2 v = *reinterpret_cast<const uint2*>(Mb + (o + loff));
        acc2p(accA, v.x); acc2p(accB, v.y);
    }

    const float4 bv = reinterpret_cast<const float4*>(b1)[ch * 64 + lane];
    const float h0 = fmaxf(fmaf(dc, accA.x, bv.x), 0.0f);
    const float h1 = fmaxf(fmaf(dc, accA.y, bv.y), 0.0f);
    const float h2 = fmaxf(fmaf(dc, accB.x, bv.z), 0.0f);
    const float h3 = fmaxf(fmaf(dc, accB.y, bv.w), 0.0f);
    nt_store8(&hB[(size_t)node * (HH / 2) + ch * 128 + lane * 2],
              pack2(h0, h1), pack2(h2, h3));
}

// ---------------------------------------------------------------------------
// Pool stage A: partial t per 32-row group, NO atomics. grid (2, 256).
// ---------------------------------------------------------------------------
__global__ __launch_bounds__(256) void k_poolA(const uint4* __restrict__ hB,
                                               const float* __restrict__ s,
                                               float* __restrict__ part) {
    const int j = blockIdx.x * 256 + threadIdx.x;      // uint4 col index
    const int c0 = blockIdx.y * (NN / PRG);            // 32 rows
    __shared__ float s_t[GG * (NN / PRG)];
    if (threadIdx.x < GG * (NN / PRG)) {
        const int g = threadIdx.x / (NN / PRG);
        const int cc = threadIdx.x % (NN / PRG);
        s_t[threadIdx.x] = s[(size_t)g * NN + c0 + cc];
    }
    __syncthreads();
    float tacc[GG][8];
    #pragma unroll
    for (int g = 0; g < GG; ++g)
        #pragma unroll
        for (int q = 0; q < 8; ++q) tacc[g][q] = 0.0f;
    for (int cc = 0; cc < NN / PRG; ++cc) {
        const uint4 v = hB[(size_t)(c0 + cc) * (HH / 8) + j];
        float hv[8];
        unpack8(v, hv);
        #pragma unroll
        for (int g = 0; g < GG; ++g) {
            const float sv = s_t[g * (NN / PRG) + cc];
            #pragma unroll
            for (int q = 0; q < 8; ++q) tacc[g][q] = fmaf(sv, hv[q], tacc[g][q]);
        }
    }
    float4* p4 = reinterpret_cast<float4*>(part);
    #pragma unroll
    for (int g = 0; g < GG; ++g) {
        const size_t base = ((size_t)(blockIdx.y * GG + g) * HH) / 4 + j * 2;
        p4[base]     = make_float4(tacc[g][0], tacc[g][1], tacc[g][2], tacc[g][3]);
        p4[base + 1] = make_float4(tacc[g][4], tacc[g][5], tacc[g][6], tacc[g][7]);
    }
}

// Pool stage B1: parts[q][g][j] = sum_{rg in [32q,32q+32)} part[rg][g][j]
// grid (32, 8) = 256 blocks.
__global__ __launch_bounds__(256) void k_poolB1(const float* __restrict__ part,
                                                float* __restrict__ parts) {
    const int idx = blockIdx.x * 256 + threadIdx.x;    // (g, j4): 8192 float4
    const int q = blockIdx.y;
    const int g = idx / (HH / 4);
    const int j4 = idx % (HH / 4);
    const float4* p4 = reinterpret_cast<const float4*>(part);
    float4 acc = make_float4(0.f, 0.f, 0.f, 0.f);
    for (int rg = q * 32; rg < q * 32 + 32; ++rg) {
        const float4 v = p4[((size_t)(rg * GG + g) * HH) / 4 + j4];
        acc.x += v.x; acc.y += v.y; acc.z += v.z; acc.w += v.w;
    }
    reinterpret_cast<float4*>(parts)[(size_t)q * (GG * HH / 4) + idx] = acc;
}

// Pool stage B2: t[g][j] = sum_q parts[q][g][j].  32 blocks.
__global__ __launch_bounds__(256) void k_poolB2(const float* __restrict__ parts,
                                                float* __restrict__ t) {
    const int idx = blockIdx.x * 256 + threadIdx.x;
    const float4* p4 = reinterpret_cast<const float4*>(parts);
    float4 acc = make_float4(0.f, 0.f, 0.f, 0.f);
    #pragma unroll
    for (int q = 0; q < 8; ++q) {
        const float4 v = p4[(size_t)q * (GG * HH / 4) + idx];
        acc.x += v.x; acc.y += v.y; acc.z += v.z; acc.w += v.w;
    }
    reinterpret_cast<float4*>(t)[idx] = acc;
}

// ---------------------------------------------------------------------------
// Final stage A: part2[jg][g][n] = sum_{j in 64-jgroup} (t[g,j]/cnt[g])*W2[j,n]
// grid (NN/1024, FJG) = (8, 64) = 512 blocks.
// ---------------------------------------------------------------------------
__global__ __launch_bounds__(256) void k_final(const float* __restrict__ W2,
                                               const float* __restrict__ t,
                                               const unsigned* __restrict__ cnt,
                                               float* __restrict__ part2) {
    __shared__ float tld[GG * 64];
    const int tj = threadIdx.x;
    const int j0 = blockIdx.y * 64;
    const int nbase = blockIdx.x * 1024;
    for (int i = threadIdx.x; i < GG * 64; i += 256) {
        const int g = i >> 6;
        const int jj = i & 63;
        unsigned c = cnt[g];
        if (c < 1u) c = 1u;
        tld[i] = t[(size_t)g * HH + j0 + jj] * (1.0f / (float)c);
    }
    __syncthreads();
    float4 acc[GG];
    #pragma unroll
    for (int g = 0; g < GG; ++g) acc[g] = make_float4(0.f, 0.f, 0.f, 0.f);
    for (int jj = 0; jj < 64; ++jj) {
        const int jv = j0 + jj;
        float4 w = reinterpret_cast<const float4*>(W2 + (size_t)jv * NN + nbase)[tj];
        #pragma unroll
        for (int g = 0; g < GG; ++g) {
            const float tv = tld[g * 64 + jj];
            acc[g].x = fmaf(tv, w.x, acc[g].x);
            acc[g].y = fmaf(tv, w.y, acc[g].y);
            acc[g].z = fmaf(tv, w.z, acc[g].z);
            acc[g].w = fmaf(tv, w.w, acc[g].w);
        }
    }
    float4* p4 = reinterpret_cast<float4*>(part2);
    #pragma unroll
    for (int g = 0; g < GG; ++g)
        p4[((size_t)(blockIdx.y * GG + g) * NN + nbase) / 4 + tj] = acc[g];
}

// Final stage B1: part3[q][g][n] = sum_{jg in [8q,8q+8)} part2[jg][g][n]
// grid (64, 8) = 512 blocks.
__global__ __launch_bounds__(256) void k_fin2a(const float* __restrict__ part2,
                                               float* __restrict__ part3) {
    const int idx = blockIdx.x * 256 + threadIdx.x;    // (g, n4): 16384 float4
    const int q = blockIdx.y;
    const int g = idx / (NN / 4);
    const int n4 = idx % (NN / 4);
    const float4* p4 = reinterpret_cast<const float4*>(part2);
    float4 acc = make_float4(0.f, 0.f, 0.f, 0.f);
    for (int jg = q * 8; jg < q * 8 + 8; ++jg) {
        const float4 v = p4[((size_t)(jg * GG + g) * NN) / 4 + n4];
        acc.x += v.x; acc.y += v.y; acc.z += v.z; acc.w += v.w;
    }
    reinterpret_cast<float4*>(part3)[(size_t)q * (GG * NN / 4) + idx] = acc;
}

// Final stage B2: out[g][n] = b2[n] + sum_q part3[q][g][n].  64 blocks.
__global__ __launch_bounds__(256) void k_fin2b(const float* __restrict__ part3,
                                               const float* __restrict__ b2,
                                               float* __restrict__ out) {
    const int idx = blockIdx.x * 256 + threadIdx.x;
    const int n4 = idx % (NN / 4);
    const float4* p4 = reinterpret_cast<const float4*>(part3);
    float4 acc = reinterpret_cast<const float4*>(b2)[n4];
    #pragma unroll
    for (int q = 0; q < 8; ++q) {
        const float4 v = p4[(size_t)q * (GG * NN / 4) + idx];
        acc.x += v.x; acc.y += v.y; acc.z += v.z; acc.w += v.w;
    }
    reinterpret_cast<float4*>(out)[idx] = acc;
}

extern "C" void kernel_launch(void* const* d_in, const int* in_sizes, int n_in,
                              void* d_out, int out_size, void* d_ws, size_t ws_size,
                              hipStream_t stream) {
    const float* x  = (const float*)d_in[0];
    const float* W1 = (const float*)d_in[1];
    const float* b1 = (const float*)d_in[2];
    const float* W2 = (const float*)d_in[3];
    const float* b2 = (const float*)d_in[4];
    const int* batch = (const int*)d_in[5];
    float* out = (float*)d_out;

    char* ws = (char*)d_ws;
    size_t off = 0;
    auto alloc = [&](size_t bytes) -> char* {
        char* p = ws + off;
        off = (off + bytes + 255) & ~(size_t)255;
        return p;
    };
    uint4*    Mh      = (uint4*)   alloc((size_t)NN * HH * 2);   // bf16 M (dinv-scaled)
    uint4*    W1h     = (uint4*)   alloc((size_t)NN * HH * 2);   // bf16 W1; REUSED as hB
    uint4*    hB      = W1h;   // h overlays W1h (dead after k_spmm1; stream-serial)
    char*     zbegin  = ws + off;
    float*    t       = (float*)   alloc((size_t)GG * HH * 4);
    unsigned* colfill = (unsigned*)alloc((size_t)NN * 4);
    unsigned* cnt     = (unsigned*)alloc((size_t)GG * 4);
    char*     zend    = ws + off;
    float*    s       = (float*)   alloc((size_t)GG * NN * 4);
    unsigned* degX    = (unsigned*)alloc((size_t)NN * 4);
    unsigned* degA    = (unsigned*)alloc((size_t)NN * 4);
    unsigned* csrX    = (unsigned*)alloc((size_t)NN * STR * 4);  // 4 MB
    unsigned* csrA    = (unsigned*)alloc((size_t)NN * STR * 4);  // 4 MB
    unsigned* cscA    = (unsigned*)alloc((size_t)NN * STR * 4);  // 4 MB
    // Tail intermediates overlay the Mh region (Mh dead after k_conv1):
    //   part  [PRG][GG][HH]   32 MiB  @ [0, 32M)
    //   part2 [FJG][GG][NN]   16 MiB  @ [32M, 48M)
    //   part3 [8][GG][NN]      2 MiB  @ [48M, 50M)
    //   parts [8][GG][HH]      1 MiB  @ [50M, 51M)
    float*    part    = (float*)Mh;
    float*    part2   = (float*)((char*)Mh + ((size_t)32 << 20));
    float*    part3   = (float*)((char*)Mh + ((size_t)48 << 20));
    float*    parts   = (float*)((char*)Mh + ((size_t)50 << 20));
    (void)ws_size; (void)in_sizes; (void)n_in; (void)out_size;

    hipMemsetAsync(zbegin, 0, (size_t)(zend - zbegin), stream);

    k_front<<<NN + (NN * HH / 8) / 256, 256, 0, stream>>>(x, W1, (uint4*)W1h, colfill,
                                                          degX, degA, csrX, csrA, cscA);
    k_s<<<NN / 4, 256, 0, stream>>>(degA, csrA, colfill, batch, s, cnt);
    k_spmm1<<<(NN / 4) * NCH, 256, 0, stream>>>((const char*)W1h, degX, csrX, colfill,
                                                (unsigned*)Mh);
    k_conv1<<<(NN / 4) * NCH, 256, 0, stream>>>((const char*)Mh, b1, colfill, cscA,
                                                (unsigned*)hB);
    k_poolA<<<dim3(HH / 2048, PRG), 256, 0, stream>>>(hB, s, part);
    k_poolB1<<<dim3(32, 8), 256, 0, stream>>>(part, parts);
    k_poolB2<<<32, 256, 0, stream>>>(parts, t);
    k_final<<<dim3(NN / 1024, FJG), 256, 0, stream>>>(W2, t, cnt, part2);
    k_fin2a<<<dim3(64, 8), 256, 0, stream>>>(part2, part3);
    k_fin2b<<<64, 256, 0, stream>>>(part3, b2, out);
}